// Round 9
// baseline (23718.048 us; speedup 1.0000x reference)
//
#include <hip/hip_runtime.h>

#define TOT   3800
#define BB    8
#define TT    1000
#define AL    0.1f

constexpr int WT_FLOATS = 4475136;   // sum of padded region blocks
constexpr int NWG       = 241;       // ITI folded into FSI wg 9's padded rows
constexpr int CMAX      = 2304;      // padded max packed-cols (576*4)

// region order: D1, D2, FSI(+ITI), GPE, STN, SNR, THAL, ALM
__constant__ int   kWgStart[9]    = {0,33,66,76,109,142,175,208,241};
__constant__ int   kRowBase[8]    = {0,520,1040,1196,1716,2236,2756,3276};
__constant__ int   kRowCnt[8]     = {520,520,156,520,520,520,520,520};
__constant__ int   kCols[8]       = {2236,2236,1200,520,520,1040,520,1040};
__constant__ int   kWtOff[8]      = {0,1180608,2361216,2553216,2827776,3102336,3651456,3926016};
__constant__ int   kWtEnd[8]      = {1180608,2361216,2553216,2827776,3102336,3651456,3926016,4475136};
__constant__ float kTonic[8]      = {0.01f,0.01f,0.01f,0.8f,0.6f,0.8f,0.01f,0.01f};
// staging segments: packed col -> global h unit index
__constant__ int   kSegStart[8][3]= {{0,2756,0},{0,2756,0},{1040,2756,3796},{520,0,0},{1196,0,0},{0,1716,0},{2236,0,0},{2756,0,0}};
__constant__ int   kSegLen[8][3]  = {{1196,1040,0},{1196,1040,0},{156,1040,4},{520,0,0},{520,0,0},{520,520,0},{520,0,0},{1040,0,0}};

struct Params {
  const float *d12d1,*d22d2,*d12d2,*d22d1,*thal2alm,*thal2d1,*thal2d2,*alm2alm,
              *alm2d1,*alm2d2,*d12snr,*d22gpe,*gpe2stn,*stn2snr,*snr2thal,
              *fsi2d1,*fsi2d2,*thal2fsi,*alm2fsi,*iti2fsi,*fsi2fsi;
  const int* mask;
};

__device__ __forceinline__ float rl(float x) { return fmaxf(x, 0.0f); }

// Build packed, pre-masked, pre-signed, ALPHA-scaled W.
// Layout per region: offset = (ugg*cols + col)*4 + j, row = ugg*4 + j
__global__ void prep_wt(Params P, float* __restrict__ Wt) {
  int e = blockIdx.x * blockDim.x + threadIdx.x;
  if (e >= WT_FLOATS) return;
  int r = 0;
  while (e >= kWtEnd[r]) ++r;
  int base  = (r == 0) ? 0 : kWtEnd[r-1];
  int local = e - base;
  int j    = local & 3;
  int q    = local >> 2;
  int cols = kCols[r];
  int col  = q % cols;
  int ugg  = q / cols;
  int row  = ugg * 4 + j;
  float v = 0.0f;
  if (row < kRowCnt[r]) {
    int c = col;
    switch (r) {
      case 0: case 1: {
        const float* pd1 = (r==0) ? P.d12d1 : P.d12d2;
        const float* pd2 = (r==0) ? P.d22d1 : P.d22d2;
        const float* pf  = (r==0) ? P.fsi2d1 : P.fsi2d2;
        const float* pt  = (r==0) ? P.thal2d1 : P.thal2d2;
        const float* pa  = (r==0) ? P.alm2d1 : P.alm2d2;
        if (c < 520)       { v = -(float)P.mask[row*520+c] * rl(pd1[row*520+c]); }
        else if (c < 1040) { int cc=c-520;  v = -(float)P.mask[row*520+cc] * rl(pd2[row*520+cc]); }
        else if (c < 1196) { int cc=c-1040; v = -rl(pf[row*156+cc]); }
        else if (c < 1716) { int cc=c-1196; v =  rl(pt[row*520+cc]); }
        else               { int cc=c-1716; v = (cc<364) ? rl(pa[row*520+cc]) : 0.0f; }
        break;
      }
      case 2: {
        if (c < 156)       { v = -rl(P.fsi2fsi[row*156+c]); }
        else if (c < 676)  { int cc=c-156; v = rl(P.thal2fsi[row*520+cc]); }
        else if (c < 1196) { int cc=c-676; v = (cc<364) ? rl(P.alm2fsi[row*520+cc]) : 0.0f; }
        else               { int cc=c-1196; v = rl(P.iti2fsi[row*4+cc]); }
        break;
      }
      case 3: v = ((row<260)==(c<260)) ? -rl(P.d22gpe[row*520+c])  : 0.0f; break;
      case 4: v = ((row<260)==(c<260)) ? -rl(P.gpe2stn[row*520+c]) : 0.0f; break;
      case 5: {
        if (c < 520) { v = ((row<260)==(c<260)) ? -rl(P.d12snr[row*520+c]) : 0.0f; }
        else { int cc=c-520; v = ((row<260)==(cc<260)) ? rl(P.stn2snr[row*520+cc]) : 0.0f; }
        break;
      }
      case 6: v = ((row<260)==(c<260)) ? -rl(P.snr2thal[row*520+c]) : 0.0f; break;
      case 7: {
        if (c < 520) { v = rl(P.thal2alm[row*520+c]); }
        else { int cc=c-520; v = rl(P.alm2alm[row*520+cc]) * ((cc<364) ? 1.0f : -1.0f); }
        break;
      }
    }
    v *= AL;
  }
  Wt[e] = v;
}

// h is u-major: hT[u*8 + b] = hn[b*TOT + u]
__global__ void init_h(const float* __restrict__ hn, float* __restrict__ h0) {
  int i = blockIdx.x * blockDim.x + threadIdx.x;
  if (i < TOT * BB) {
    int u = i >> 3, b = i & 7;
    h0[i] = hn[b * TOT + u];
  }
}

__global__ void zero_bar(unsigned* __restrict__ bar) {
  if (threadIdx.x < 272) bar[threadIdx.x] = 0u;
}

__device__ __forceinline__ float2 agld2(const float* p) {
  unsigned long long v = __hip_atomic_load((const unsigned long long*)p,
                                           __ATOMIC_RELAXED, __HIP_MEMORY_SCOPE_AGENT);
  float2 r;
  r.x = __uint_as_float((unsigned)(v & 0xffffffffull));
  r.y = __uint_as_float((unsigned)(v >> 32));
  return r;
}
__device__ __forceinline__ void agst2(float* p, float a, float b) {
  unsigned long long v = ((unsigned long long)__float_as_uint(b) << 32) | __float_as_uint(a);
  __hip_atomic_store((unsigned long long*)p, v, __ATOMIC_RELAXED, __HIP_MEMORY_SCOPE_AGENT);
}

#define CF(W, HX, BI) \
  acc[0][BI] = fmaf((W).x, (HX), acc[0][BI]); \
  acc[1][BI] = fmaf((W).y, (HX), acc[1][BI]); \
  acc[2][BI] = fmaf((W).z, (HX), acc[2][BI]); \
  acc[3][BI] = fmaf((W).w, (HX), acc[3][BI]);

// 1024 threads/WG, 16 waves, 1 WG/CU. R4's register structure (w[9]=36 VGPR,
// acc[4][8]=32 — empirically no-spill at the 64-VGPR cap via AGPR absorption)
// + column-major h in LDS (stride 12 floats) so batch reads are ds_read_b128.
// All LDS phases are <=2-way bank aliasing (free) or measured conflict-free.
__global__ void __launch_bounds__(1024)
rnn_scan(const float* __restrict__ Wt, const float* __restrict__ noise,
         const float* __restrict__ inp, float* __restrict__ out,
         float* __restrict__ h0, float* __restrict__ h1,
         unsigned* __restrict__ bar) {
  __shared__ float4 S4[8192];        // 131072 B union
  float* Sh = (float*)S4;            // h: Sh[c*12 + b], c < 2304 (110.6 KB)
  const int bid = blockIdx.x, tid = threadIdx.x;
  int r = 0;
  while (bid >= kWgStart[r + 1]) ++r;

  unsigned* cnt1 = bar;              // 8 groups, stride 32 words
  unsigned* cnt0 = bar + 256;
  unsigned* flag = bar + 257;
  const int g8   = bid & 7;
  const unsigned gsz = (g8 == 0) ? 31u : 30u;

  const int wgl     = bid - kWgStart[r];
  const int cols    = kCols[r];
  const int rowcnt  = kRowCnt[r];
  const int rowbase = kRowBase[r];
  const int rg = tid >> 8, sp = tid & 255;
  const float* wtp = Wt + (size_t)kWtOff[r];
  const float ton = kTonic[r];
  const int l0 = kSegLen[r][0], l1 = kSegLen[r][1];
  const int g0 = kSegStart[r][0], g1 = kSegStart[r][1], g2 = kSegStart[r][2];

  // ---- W fragments: w[i] = quad-rows of col c = sp + 256*i  (36 VGPR)
  float4 w[9];
  {
    const int ug = wgl * 4 + rg;
    const float* wb = wtp + (size_t)ug * cols * 4;
    #pragma unroll
    for (int i = 0; i < 9; ++i) {
      int c = sp + (i << 8);
      w[i] = (c < cols) ? *(const float4*)(wb + (size_t)c * 4) : make_float4(0,0,0,0);
    }
  }

  // ---- t-invariant staging tasks: task = c*2 + half  (4608 tasks)
  // pk = ((go+1)<<15) | ds ; go = -1 => zero-fill ; pk = -1 => no task
  int pkk[5];
  #pragma unroll
  for (int k2 = 0; k2 < 5; ++k2) {
    int task = tid + (k2 << 10);
    if (task < 2 * CMAX) {
      int c = task >> 1, half = task & 1;
      int go = -1;
      if (c < cols) {
        int g;
        if (c < l0)           g = g0 + c;
        else if (c < l0 + l1) g = g1 + (c - l0);
        else                  g = g2 + (c - l0 - l1);
        go = g * 8 + half * 4;
      }
      pkk[k2] = ((go + 1) << 15) | (c * 12 + half * 4);
    } else pkk[k2] = -1;
  }

  // ---- epilogue owner: tid&31==0 owns (row = ri>>1, b-quad bh = ri&1)
  const int  ri    = tid >> 5, kk = tid & 31;
  const int  erow  = ri >> 1, bh = ri & 1, eb0 = bh * 4;
  const int  erowl = wgl * 16 + erow;
  const bool eiti  = (r == 2) && (wgl == 9) && (kk == 0) && (erowl >= 156);
  const bool ewr   = (kk == 0) && (erowl < rowcnt);
  const int  erg   = eiti ? (3796 + (erowl - 156)) : (rowbase + erowl);
  const bool own   = ewr || eiti;
  const float tonf = eiti ? 0.0f : ton;
  const size_t SB  = (size_t)TT * TOT;

  float4 hp = {0,0,0,0}, nz = {0,0,0,0}, ii = {0,0,0,0};
  if (own) {
    hp.x = h0[erg*8 + eb0+0]; hp.y = h0[erg*8 + eb0+1];
    hp.z = h0[erg*8 + eb0+2]; hp.w = h0[erg*8 + eb0+3];
    const float* np = noise + erg;
    nz.x = np[(eb0+0)*SB]; nz.y = np[(eb0+1)*SB];
    nz.z = np[(eb0+2)*SB]; nz.w = np[(eb0+3)*SB];
    if (eiti) {
      int ik = erg - 3796;
      ii.x = inp[((size_t)(eb0+0)*TT)*4 + ik]; ii.y = inp[((size_t)(eb0+1)*TT)*4 + ik];
      ii.z = inp[((size_t)(eb0+2)*TT)*4 + ik]; ii.w = inp[((size_t)(eb0+3)*TT)*4 + ik];
    }
  }

  for (int t = 0; t < TT; ++t) {
    const float* __restrict__ hc = (t & 1) ? h1 : h0;
    float*       __restrict__ hx = (t & 1) ? h0 : h1;

    // ---- stage: Sh[c*12 + half*4 .. +3] = hT[g][half*4 .. +3]  (b128 writes)
    #pragma unroll
    for (int k2 = 0; k2 < 5; ++k2) {
      int pk = pkk[k2];
      if (pk >= 0) {
        int ds = pk & 32767;
        int go = (pk >> 15) - 1;
        float4 v = make_float4(0.f, 0.f, 0.f, 0.f);
        if (go >= 0) {
          float2 a  = agld2(hc + go);
          float2 b2 = agld2(hc + go + 2);
          v = make_float4(a.x, a.y, b2.x, b2.y);
        }
        *(float4*)(Sh + ds) = v;
      }
    }
    __syncthreads();

    // ---- FMA: per col, 2x ds_read_b128 (8 batches) -> 32 FMAs
    float acc[4][8];
    #pragma unroll
    for (int r2 = 0; r2 < 4; ++r2)
      #pragma unroll
      for (int b = 0; b < 8; ++b) acc[r2][b] = 0.f;

    #pragma unroll
    for (int i = 0; i < 9; ++i) {
      const float4 hv0 = *(const float4*)(Sh + sp*12 + i*3072);
      const float4 hv1 = *(const float4*)(Sh + sp*12 + i*3072 + 4);
      const float4 wv = w[i];
      CF(wv, hv0.x, 0) CF(wv, hv0.y, 1) CF(wv, hv0.z, 2) CF(wv, hv0.w, 3)
      CF(wv, hv1.x, 4) CF(wv, hv1.y, 5) CF(wv, hv1.z, 6) CF(wv, hv1.w, 7)
    }
    __syncthreads();   // done reading h; reuse S4 as partials

    // ---- partials: S4[(row16*2+bh)*256 + sp] (contiguous b128, R5: 0 conflicts)
    #pragma unroll
    for (int r2 = 0; r2 < 4; ++r2) {
      S4[(((rg * 4 + r2) << 1) | 0) * 256 + sp] = make_float4(acc[r2][0], acc[r2][1], acc[r2][2], acc[r2][3]);
      S4[(((rg * 4 + r2) << 1) | 1) * 256 + sp] = make_float4(acc[r2][4], acc[r2][5], acc[r2][6], acc[r2][7]);
    }
    __syncthreads();

    // ---- reduce: group ri (32 lanes) sums 256 sp slots, then 5-level shfl
    float4 sv = {0,0,0,0};
    #pragma unroll
    for (int it = 0; it < 8; ++it) {
      float4 p = S4[ri * 256 + kk + (it << 5)];
      sv.x += p.x; sv.y += p.y; sv.z += p.z; sv.w += p.w;
    }
    #pragma unroll
    for (int m = 1; m <= 16; m <<= 1) {
      sv.x += __shfl_xor(sv.x, m);
      sv.y += __shfl_xor(sv.y, m);
      sv.z += __shfl_xor(sv.z, m);
      sv.w += __shfl_xor(sv.w, m);
    }

    float4 x = {0,0,0,0};
    if (own) {
      x.x = fmaxf(fmaf(0.9f, hp.x, sv.x + AL * (tonf + nz.x + ii.x)), 0.0f);
      x.y = fmaxf(fmaf(0.9f, hp.y, sv.y + AL * (tonf + nz.y + ii.y)), 0.0f);
      x.z = fmaxf(fmaf(0.9f, hp.z, sv.z + AL * (tonf + nz.z + ii.z)), 0.0f);
      x.w = fmaxf(fmaf(0.9f, hp.w, sv.w + AL * (tonf + nz.w + ii.w)), 0.0f);
      agst2(&hx[erg*8 + eb0],     x.x, x.y);
      agst2(&hx[erg*8 + eb0 + 2], x.z, x.w);
    }
    __syncthreads();   // drain hx stores (vmcnt(0) before s_barrier)

    // ---- arrive (release: all WG stores LLC-acked before the count)
    if (tid == 0) {
      unsigned old = atomicAdd(&cnt1[g8 * 32], 1u);
      if (old + 1 == gsz * (unsigned)(t + 1)) {
        unsigned o0 = atomicAdd(cnt0, 1u);
        if (o0 + 1 == 8u * (unsigned)(t + 1)) {
          __hip_atomic_store(flag, (unsigned)(t + 1), __ATOMIC_RELAXED, __HIP_MEMORY_SCOPE_AGENT);
        }
      }
    }

    // ---- independent work hidden under the barrier: out-store + t+1 prefetch
    if (own) {
      float* op = out + (size_t)eb0 * SB + (size_t)t * TOT + erg;
      op[0] = x.x; op[SB] = x.y; op[2*SB] = x.z; op[3*SB] = x.w;
      hp = x;
      if (t + 1 < TT) {
        const float* np = noise + erg + (size_t)(t + 1) * TOT;
        nz.x = np[(eb0+0)*SB]; nz.y = np[(eb0+1)*SB];
        nz.z = np[(eb0+2)*SB]; nz.w = np[(eb0+3)*SB];
        if (eiti) {
          int ik = erg - 3796;
          const float* ip = inp + (size_t)(t + 1) * 4 + ik;
          ii.x = ip[(size_t)(eb0+0)*TT*4]; ii.y = ip[(size_t)(eb0+1)*TT*4];
          ii.z = ip[(size_t)(eb0+2)*TT*4]; ii.w = ip[(size_t)(eb0+3)*TT*4];
        }
      }
    }

    // ---- wait
    if (tid == 0) {
      while (__hip_atomic_load(flag, __ATOMIC_RELAXED, __HIP_MEMORY_SCOPE_AGENT) < (unsigned)(t + 1)) {}
    }
    __syncthreads();
  }
}

extern "C" void kernel_launch(void* const* d_in, const int* in_sizes, int n_in,
                              void* d_out, int out_size, void* d_ws, size_t ws_size,
                              hipStream_t stream) {
  Params P;
  P.d12d1   = (const float*)d_in[0];  P.d22d2   = (const float*)d_in[1];
  P.d12d2   = (const float*)d_in[2];  P.d22d1   = (const float*)d_in[3];
  P.thal2alm= (const float*)d_in[4];  P.thal2d1 = (const float*)d_in[5];
  P.thal2d2 = (const float*)d_in[6];  P.alm2alm = (const float*)d_in[7];
  P.alm2d1  = (const float*)d_in[8];  P.alm2d2  = (const float*)d_in[9];
  P.d12snr  = (const float*)d_in[10]; P.d22gpe  = (const float*)d_in[11];
  P.gpe2stn = (const float*)d_in[12]; P.stn2snr = (const float*)d_in[13];
  P.snr2thal= (const float*)d_in[14]; P.fsi2d1  = (const float*)d_in[15];
  P.fsi2d2  = (const float*)d_in[16]; P.thal2fsi= (const float*)d_in[17];
  P.alm2fsi = (const float*)d_in[18]; P.iti2fsi = (const float*)d_in[19];
  P.fsi2fsi = (const float*)d_in[20]; P.mask    = (const int*)d_in[21];
  const float* inp   = (const float*)d_in[22];
  const float* hn    = (const float*)d_in[23];
  const float* noise = (const float*)d_in[24];

  float* ws = (float*)d_ws;
  float* Wt = ws;
  float* h0 = ws + WT_FLOATS;
  float* h1 = h0 + TOT * BB;
  unsigned* bar = (unsigned*)(h1 + TOT * BB);

  hipLaunchKernelGGL(prep_wt,  dim3((WT_FLOATS + 255) / 256), dim3(256), 0, stream, P, Wt);
  hipLaunchKernelGGL(init_h,   dim3((TOT * BB + 255) / 256),  dim3(256), 0, stream, hn, h0);
  hipLaunchKernelGGL(zero_bar, dim3(1), dim3(512), 0, stream, bar);

  const float* WtA = Wt; const float* noiseA = noise; const float* inpA = inp;
  float* outA = (float*)d_out; float* h0A = h0; float* h1A = h1; unsigned* barA = bar;
  void* kargs[7] = {&WtA, &noiseA, &inpA, &outA, &h0A, &h1A, &barA};
  hipLaunchCooperativeKernel((const void*)rnn_scan, dim3(NWG), dim3(1024), kargs, 0, stream);
}

// Round 10
// 20474.066 us; speedup vs baseline: 1.1584x; 1.1584x over previous
//
#include <hip/hip_runtime.h>

#define TOT   3800
#define BB    8
#define TT    1000
#define AL    0.1f

constexpr int WT_FLOATS = 4475136;   // sum of padded region blocks
constexpr int NWG       = 241;       // ITI folded into FSI wg 9's padded rows
constexpr int CMAX      = 2304;      // padded packed-col count

// region order: D1, D2, FSI(+ITI), GPE, STN, SNR, THAL, ALM
__constant__ int   kWgStart[9]    = {0,33,66,76,109,142,175,208,241};
__constant__ int   kRowBase[8]    = {0,520,1040,1196,1716,2236,2756,3276};
__constant__ int   kRowCnt[8]     = {520,520,156,520,520,520,520,520};
__constant__ int   kCols[8]       = {2236,2236,1200,520,520,1040,520,1040};
__constant__ int   kWtOff[8]      = {0,1180608,2361216,2553216,2827776,3102336,3651456,3926016};
__constant__ int   kWtEnd[8]      = {1180608,2361216,2553216,2827776,3102336,3651456,3926016,4475136};
__constant__ float kTonic[8]      = {0.01f,0.01f,0.01f,0.8f,0.6f,0.8f,0.01f,0.01f};
// staging segments: packed col -> global h unit index
__constant__ int   kSegStart[8][3]= {{0,2756,0},{0,2756,0},{1040,2756,3796},{520,0,0},{1196,0,0},{0,1716,0},{2236,0,0},{2756,0,0}};
__constant__ int   kSegLen[8][3]  = {{1196,1040,0},{1196,1040,0},{156,1040,4},{520,0,0},{520,0,0},{520,520,0},{520,0,0},{1040,0,0}};

struct Params {
  const float *d12d1,*d22d2,*d12d2,*d22d1,*thal2alm,*thal2d1,*thal2d2,*alm2alm,
              *alm2d1,*alm2d2,*d12snr,*d22gpe,*gpe2stn,*stn2snr,*snr2thal,
              *fsi2d1,*fsi2d2,*thal2fsi,*alm2fsi,*iti2fsi,*fsi2fsi;
  const int* mask;
};

__device__ __forceinline__ float rl(float x) { return fmaxf(x, 0.0f); }

// Build packed, pre-masked, pre-signed, ALPHA-scaled W.
// Layout per region: offset = (ugg*cols + col)*4 + j, row = ugg*4 + j
__global__ void prep_wt(Params P, float* __restrict__ Wt) {
  int e = blockIdx.x * blockDim.x + threadIdx.x;
  if (e >= WT_FLOATS) return;
  int r = 0;
  while (e >= kWtEnd[r]) ++r;
  int base  = (r == 0) ? 0 : kWtEnd[r-1];
  int local = e - base;
  int j    = local & 3;
  int q    = local >> 2;
  int cols = kCols[r];
  int col  = q % cols;
  int ugg  = q / cols;
  int row  = ugg * 4 + j;
  float v = 0.0f;
  if (row < kRowCnt[r]) {
    int c = col;
    switch (r) {
      case 0: case 1: {
        const float* pd1 = (r==0) ? P.d12d1 : P.d12d2;
        const float* pd2 = (r==0) ? P.d22d1 : P.d22d2;
        const float* pf  = (r==0) ? P.fsi2d1 : P.fsi2d2;
        const float* pt  = (r==0) ? P.thal2d1 : P.thal2d2;
        const float* pa  = (r==0) ? P.alm2d1 : P.alm2d2;
        if (c < 520)       { v = -(float)P.mask[row*520+c] * rl(pd1[row*520+c]); }
        else if (c < 1040) { int cc=c-520;  v = -(float)P.mask[row*520+cc] * rl(pd2[row*520+cc]); }
        else if (c < 1196) { int cc=c-1040; v = -rl(pf[row*156+cc]); }
        else if (c < 1716) { int cc=c-1196; v =  rl(pt[row*520+cc]); }
        else               { int cc=c-1716; v = (cc<364) ? rl(pa[row*520+cc]) : 0.0f; }
        break;
      }
      case 2: {
        if (c < 156)       { v = -rl(P.fsi2fsi[row*156+c]); }
        else if (c < 676)  { int cc=c-156; v = rl(P.thal2fsi[row*520+cc]); }
        else if (c < 1196) { int cc=c-676; v = (cc<364) ? rl(P.alm2fsi[row*520+cc]) : 0.0f; }
        else               { int cc=c-1196; v = rl(P.iti2fsi[row*4+cc]); }
        break;
      }
      case 3: v = ((row<260)==(c<260)) ? -rl(P.d22gpe[row*520+c])  : 0.0f; break;
      case 4: v = ((row<260)==(c<260)) ? -rl(P.gpe2stn[row*520+c]) : 0.0f; break;
      case 5: {
        if (c < 520) { v = ((row<260)==(c<260)) ? -rl(P.d12snr[row*520+c]) : 0.0f; }
        else { int cc=c-520; v = ((row<260)==(cc<260)) ? rl(P.stn2snr[row*520+cc]) : 0.0f; }
        break;
      }
      case 6: v = ((row<260)==(c<260)) ? -rl(P.snr2thal[row*520+c]) : 0.0f; break;
      case 7: {
        if (c < 520) { v = rl(P.thal2alm[row*520+c]); }
        else { int cc=c-520; v = rl(P.alm2alm[row*520+cc]) * ((cc<364) ? 1.0f : -1.0f); }
        break;
      }
    }
    v *= AL;
  }
  Wt[e] = v;
}

// h is u-major: hT[u*8 + b] = hn[b*TOT + u]
__global__ void init_h(const float* __restrict__ hn, float* __restrict__ h0) {
  int i = blockIdx.x * blockDim.x + threadIdx.x;
  if (i < TOT * BB) {
    int u = i >> 3, b = i & 7;
    h0[i] = hn[b * TOT + u];
  }
}

__global__ void zero_bar(unsigned* __restrict__ bar) {
  if (threadIdx.x < 272) bar[threadIdx.x] = 0u;
}

__device__ __forceinline__ float2 agld2(const float* p) {
  unsigned long long v = __hip_atomic_load((const unsigned long long*)p,
                                           __ATOMIC_RELAXED, __HIP_MEMORY_SCOPE_AGENT);
  float2 r;
  r.x = __uint_as_float((unsigned)(v & 0xffffffffull));
  r.y = __uint_as_float((unsigned)(v >> 32));
  return r;
}
__device__ __forceinline__ void agst2(float* p, float a, float b) {
  unsigned long long v = ((unsigned long long)__float_as_uint(b) << 32) | __float_as_uint(a);
  __hip_atomic_store((unsigned long long*)p, v, __ATOMIC_RELAXED, __HIP_MEMORY_SCOPE_AGENT);
}

#define CF(W, HX) \
  acc[0][b] = fmaf((W).x, (HX), acc[0][b]); \
  acc[1][b] = fmaf((W).y, (HX), acc[1][b]); \
  acc[2][b] = fmaf((W).z, (HX), acc[2][b]); \
  acc[3][b] = fmaf((W).w, (HX), acc[3][b]);

// R4 structure (proven no-spill at 64-VGPR: scalar inner reads, w[9]+acc[4][8])
// + float4 partials/reduce (R5-proven conflict-free) + packed staging tasks.
__global__ void __launch_bounds__(1024, 4)
rnn_scan(const float* __restrict__ Wt, const float* __restrict__ noise,
         const float* __restrict__ inp, float* __restrict__ out,
         float* __restrict__ h0, float* __restrict__ h1,
         unsigned* __restrict__ bar) {
  __shared__ float4 S4[8192];     // union: h floats [8][2308] (18464 f) / partials [32][256] f4
  float* S = (float*)S4;
  const int bid = blockIdx.x, tid = threadIdx.x;
  int r = 0;
  while (bid >= kWgStart[r + 1]) ++r;

  unsigned* cnt1 = bar;           // 8 groups, stride 32 words
  unsigned* cnt0 = bar + 256;
  unsigned* flag = bar + 257;
  const int g8   = bid & 7;
  const unsigned gsz = (g8 == 0) ? 31u : 30u;

  const int wgl     = bid - kWgStart[r];
  const int cols    = kCols[r];
  const int rowcnt  = kRowCnt[r];
  const int rowbase = kRowBase[r];
  const int rg = tid >> 8, sp = tid & 255;
  const float* wtp = Wt + (size_t)kWtOff[r];
  const float ton = kTonic[r];
  const int l0 = kSegLen[r][0], l1 = kSegLen[r][1];
  const int g0 = kSegStart[r][0], g1 = kSegStart[r][1], g2 = kSegStart[r][2];

  // ---- W fragments: w[i] = quad-rows of col c = sp + 256*i  (36 VGPR)
  float4 w[9];
  {
    const int ug = wgl * 4 + rg;
    const float* wb = wtp + (size_t)ug * cols * 4;
    #pragma unroll
    for (int i = 0; i < 9; ++i) {
      int c = sp + (i << 8);
      w[i] = (c < cols) ? *(const float4*)(wb + (size_t)c * 4) : make_float4(0,0,0,0);
    }
  }

  // ---- staging tasks: task = c*2 + half (4608). Per task: 2 agld2 (unit g,
  // batches half*4..+3) -> 4 scalar LDS writes S[(half*4+q)*2308 + c].
  // pk = ((go+1)<<13) | (c<<1) | half ; go=-1 => zero-fill ; pk=-1 => no task
  int pkk[5];
  #pragma unroll
  for (int k2 = 0; k2 < 5; ++k2) {
    int task = tid + (k2 << 10);
    if (task < 2 * CMAX) {
      int c = task >> 1, half = task & 1;
      int go = -1;
      if (c < cols) {
        int g;
        if (c < l0)           g = g0 + c;
        else if (c < l0 + l1) g = g1 + (c - l0);
        else                  g = g2 + (c - l0 - l1);
        go = g * 8 + half * 4;
      }
      pkk[k2] = ((go + 1) << 13) | task;
    } else pkk[k2] = -1;
  }

  // ---- reduce/epilogue: 32-lane group ri = tid>>5 in [0,32) = (row = ri>>1, bh = ri&1)
  const int  ri    = tid >> 5, kk = tid & 31;
  const int  erow  = ri >> 1, bh = ri & 1, eb0 = bh * 4;
  const int  erowl = wgl * 16 + erow;
  const bool eiti  = (r == 2) && (wgl == 9) && (kk == 0) && (erowl >= 156);
  const bool ewr   = (kk == 0) && (erowl < rowcnt);
  const int  erg   = eiti ? (3796 + (erowl - 156)) : (rowbase + erowl);
  const bool own   = ewr || eiti;
  const float tonf = eiti ? 0.0f : ton;
  const size_t SB  = (size_t)TT * TOT;

  float4 hp = {0,0,0,0}, nz = {0,0,0,0}, ii = {0,0,0,0};
  if (own) {
    hp.x = h0[erg*8 + eb0+0]; hp.y = h0[erg*8 + eb0+1];
    hp.z = h0[erg*8 + eb0+2]; hp.w = h0[erg*8 + eb0+3];
    const float* np = noise + erg;
    nz.x = np[(size_t)(eb0+0)*SB]; nz.y = np[(size_t)(eb0+1)*SB];
    nz.z = np[(size_t)(eb0+2)*SB]; nz.w = np[(size_t)(eb0+3)*SB];
    if (eiti) {
      int ik = erg - 3796;
      ii.x = inp[((size_t)(eb0+0)*TT)*4 + ik]; ii.y = inp[((size_t)(eb0+1)*TT)*4 + ik];
      ii.z = inp[((size_t)(eb0+2)*TT)*4 + ik]; ii.w = inp[((size_t)(eb0+3)*TT)*4 + ik];
    }
  }

  for (int t = 0; t < TT; ++t) {
    const float* __restrict__ hc = (t & 1) ? h1 : h0;
    float*       __restrict__ hx = (t & 1) ? h0 : h1;

    // ---- stage h: S[b*2308 + c]  (2x b64 agent loads, 4 scalar LDS writes/task)
    #pragma unroll
    for (int k2 = 0; k2 < 5; ++k2) {
      int pk = pkk[k2];
      if (pk >= 0) {
        int c    = (pk >> 1) & 4095;
        int half = pk & 1;
        int go   = (pk >> 13) - 1;
        float4 v = make_float4(0.f, 0.f, 0.f, 0.f);
        if (go >= 0) {
          float2 a  = agld2(hc + go);
          float2 b2 = agld2(hc + go + 2);
          v = make_float4(a.x, a.y, b2.x, b2.y);
        }
        int b0 = half * 4;
        S[(b0+0)*2308 + c] = v.x;
        S[(b0+1)*2308 + c] = v.y;
        S[(b0+2)*2308 + c] = v.z;
        S[(b0+3)*2308 + c] = v.w;
      }
    }
    __syncthreads();

    // ---- FMA burst: 72 conflict-free scalar reads + 288 fmaf (R4-exact shape)
    float acc[4][8];
    #pragma unroll
    for (int r2 = 0; r2 < 4; ++r2)
      #pragma unroll
      for (int b = 0; b < 8; ++b) acc[r2][b] = 0.f;

    #pragma unroll
    for (int i = 0; i < 9; ++i) {
      const float4 wv = w[i];
      const int c = sp + (i << 8);
      #pragma unroll
      for (int b = 0; b < 8; ++b) {
        const float h = S[b * 2308 + c];
        CF(wv, h)
      }
    }
    __syncthreads();   // done reading h; reuse S4 as partials

    // ---- partials: S4[(row16*2+bhalf)*256 + sp]  (contiguous b128, conflict-free)
    #pragma unroll
    for (int r2 = 0; r2 < 4; ++r2) {
      S4[(((rg * 4 + r2) << 1) | 0) * 256 + sp] = make_float4(acc[r2][0], acc[r2][1], acc[r2][2], acc[r2][3]);
      S4[(((rg * 4 + r2) << 1) | 1) * 256 + sp] = make_float4(acc[r2][4], acc[r2][5], acc[r2][6], acc[r2][7]);
    }
    __syncthreads();

    // ---- reduce: group ri (32 lanes) sums 256 sp slots (8x b128), 5-level shfl
    float4 sv = {0,0,0,0};
    #pragma unroll
    for (int it = 0; it < 8; ++it) {
      float4 p = S4[ri * 256 + kk + (it << 5)];
      sv.x += p.x; sv.y += p.y; sv.z += p.z; sv.w += p.w;
    }
    #pragma unroll
    for (int m = 1; m <= 16; m <<= 1) {
      sv.x += __shfl_xor(sv.x, m);
      sv.y += __shfl_xor(sv.y, m);
      sv.z += __shfl_xor(sv.z, m);
      sv.w += __shfl_xor(sv.w, m);
    }

    float4 x = {0,0,0,0};
    if (own) {
      x.x = fmaxf(fmaf(0.9f, hp.x, sv.x + AL * (tonf + nz.x + ii.x)), 0.0f);
      x.y = fmaxf(fmaf(0.9f, hp.y, sv.y + AL * (tonf + nz.y + ii.y)), 0.0f);
      x.z = fmaxf(fmaf(0.9f, hp.z, sv.z + AL * (tonf + nz.z + ii.z)), 0.0f);
      x.w = fmaxf(fmaf(0.9f, hp.w, sv.w + AL * (tonf + nz.w + ii.w)), 0.0f);
      agst2(&hx[erg*8 + eb0],     x.x, x.y);
      agst2(&hx[erg*8 + eb0 + 2], x.z, x.w);
    }
    __syncthreads();   // drain hx stores (vmcnt(0) before s_barrier)

    // ---- arrive (release: all WG stores LLC-acked before the count)
    if (tid == 0) {
      unsigned old = atomicAdd(&cnt1[g8 * 32], 1u);
      if (old + 1 == gsz * (unsigned)(t + 1)) {
        unsigned o0 = atomicAdd(cnt0, 1u);
        if (o0 + 1 == 8u * (unsigned)(t + 1)) {
          __hip_atomic_store(flag, (unsigned)(t + 1), __ATOMIC_RELAXED, __HIP_MEMORY_SCOPE_AGENT);
        }
      }
    }

    // ---- independent work hidden under the barrier: out-store + t+1 prefetch
    if (own) {
      float* op = out + (size_t)eb0 * SB + (size_t)t * TOT + erg;
      op[0] = x.x; op[SB] = x.y; op[2*SB] = x.z; op[3*SB] = x.w;
      hp = x;
      if (t + 1 < TT) {
        const float* np = noise + erg + (size_t)(t + 1) * TOT;
        nz.x = np[(size_t)(eb0+0)*SB]; nz.y = np[(size_t)(eb0+1)*SB];
        nz.z = np[(size_t)(eb0+2)*SB]; nz.w = np[(size_t)(eb0+3)*SB];
        if (eiti) {
          int ik = erg - 3796;
          const float* ip = inp + (size_t)(t + 1) * 4 + ik;
          ii.x = ip[(size_t)(eb0+0)*TT*4]; ii.y = ip[(size_t)(eb0+1)*TT*4];
          ii.z = ip[(size_t)(eb0+2)*TT*4]; ii.w = ip[(size_t)(eb0+3)*TT*4];
        }
      }
    }

    // ---- wait
    if (tid == 0) {
      while (__hip_atomic_load(flag, __ATOMIC_RELAXED, __HIP_MEMORY_SCOPE_AGENT) < (unsigned)(t + 1)) {}
    }
    __syncthreads();
  }
}

extern "C" void kernel_launch(void* const* d_in, const int* in_sizes, int n_in,
                              void* d_out, int out_size, void* d_ws, size_t ws_size,
                              hipStream_t stream) {
  Params P;
  P.d12d1   = (const float*)d_in[0];  P.d22d2   = (const float*)d_in[1];
  P.d12d2   = (const float*)d_in[2];  P.d22d1   = (const float*)d_in[3];
  P.thal2alm= (const float*)d_in[4];  P.thal2d1 = (const float*)d_in[5];
  P.thal2d2 = (const float*)d_in[6];  P.alm2alm = (const float*)d_in[7];
  P.alm2d1  = (const float*)d_in[8];  P.alm2d2  = (const float*)d_in[9];
  P.d12snr  = (const float*)d_in[10]; P.d22gpe  = (const float*)d_in[11];
  P.gpe2stn = (const float*)d_in[12]; P.stn2snr = (const float*)d_in[13];
  P.snr2thal= (const float*)d_in[14]; P.fsi2d1  = (const float*)d_in[15];
  P.fsi2d2  = (const float*)d_in[16]; P.thal2fsi= (const float*)d_in[17];
  P.alm2fsi = (const float*)d_in[18]; P.iti2fsi = (const float*)d_in[19];
  P.fsi2fsi = (const float*)d_in[20]; P.mask    = (const int*)d_in[21];
  const float* inp   = (const float*)d_in[22];
  const float* hn    = (const float*)d_in[23];
  const float* noise = (const float*)d_in[24];

  float* ws = (float*)d_ws;
  float* Wt = ws;
  float* h0 = ws + WT_FLOATS;
  float* h1 = h0 + TOT * BB;
  unsigned* bar = (unsigned*)(h1 + TOT * BB);

  hipLaunchKernelGGL(prep_wt,  dim3((WT_FLOATS + 255) / 256), dim3(256), 0, stream, P, Wt);
  hipLaunchKernelGGL(init_h,   dim3((TOT * BB + 255) / 256),  dim3(256), 0, stream, hn, h0);
  hipLaunchKernelGGL(zero_bar, dim3(1), dim3(512), 0, stream, bar);

  const float* WtA = Wt; const float* noiseA = noise; const float* inpA = inp;
  float* outA = (float*)d_out; float* h0A = h0; float* h1A = h1; unsigned* barA = bar;
  void* kargs[7] = {&WtA, &noiseA, &inpA, &outA, &h0A, &h1A, &barA};
  hipLaunchCooperativeKernel((const void*)rnn_scan, dim3(NWG), dim3(1024), kargs, 0, stream);
}

// Round 11
// 7757.672 us; speedup vs baseline: 3.0574x; 2.6392x over previous
//
#include <hip/hip_runtime.h>

#define TOT   3800
#define BB    8
#define TT    1000
#define AL    0.1f

constexpr int WT_FLOATS = 4475136;   // sum of padded region blocks
constexpr int NWG       = 241;       // ITI folded into FSI wg 9's padded rows
constexpr int CMAX      = 2304;      // padded packed-col count

// region order: D1, D2, FSI(+ITI), GPE, STN, SNR, THAL, ALM
__constant__ int   kWgStart[9]    = {0,33,66,76,109,142,175,208,241};
__constant__ int   kRowBase[8]    = {0,520,1040,1196,1716,2236,2756,3276};
__constant__ int   kRowCnt[8]     = {520,520,156,520,520,520,520,520};
__constant__ int   kCols[8]       = {2236,2236,1200,520,520,1040,520,1040};
__constant__ int   kWtOff[8]      = {0,1180608,2361216,2553216,2827776,3102336,3651456,3926016};
__constant__ int   kWtEnd[8]      = {1180608,2361216,2553216,2827776,3102336,3651456,3926016,4475136};
__constant__ float kTonic[8]      = {0.01f,0.01f,0.01f,0.8f,0.6f,0.8f,0.01f,0.01f};
// staging segments: packed col -> global h unit index
__constant__ int   kSegStart[8][3]= {{0,2756,0},{0,2756,0},{1040,2756,3796},{520,0,0},{1196,0,0},{0,1716,0},{2236,0,0},{2756,0,0}};
__constant__ int   kSegLen[8][3]  = {{1196,1040,0},{1196,1040,0},{156,1040,4},{520,0,0},{520,0,0},{520,520,0},{520,0,0},{1040,0,0}};

struct Params {
  const float *d12d1,*d22d2,*d12d2,*d22d1,*thal2alm,*thal2d1,*thal2d2,*alm2alm,
              *alm2d1,*alm2d2,*d12snr,*d22gpe,*gpe2stn,*stn2snr,*snr2thal,
              *fsi2d1,*fsi2d2,*thal2fsi,*alm2fsi,*iti2fsi,*fsi2fsi;
  const int* mask;
};

__device__ __forceinline__ float rl(float x) { return fmaxf(x, 0.0f); }

// Build packed, pre-masked, pre-signed, ALPHA-scaled W.
// Layout per region: offset = (ugg*cols + col)*4 + j, row = ugg*4 + j
__global__ void prep_wt(Params P, float* __restrict__ Wt) {
  int e = blockIdx.x * blockDim.x + threadIdx.x;
  if (e >= WT_FLOATS) return;
  int r = 0;
  while (e >= kWtEnd[r]) ++r;
  int base  = (r == 0) ? 0 : kWtEnd[r-1];
  int local = e - base;
  int j    = local & 3;
  int q    = local >> 2;
  int cols = kCols[r];
  int col  = q % cols;
  int ugg  = q / cols;
  int row  = ugg * 4 + j;
  float v = 0.0f;
  if (row < kRowCnt[r]) {
    int c = col;
    switch (r) {
      case 0: case 1: {
        const float* pd1 = (r==0) ? P.d12d1 : P.d12d2;
        const float* pd2 = (r==0) ? P.d22d1 : P.d22d2;
        const float* pf  = (r==0) ? P.fsi2d1 : P.fsi2d2;
        const float* pt  = (r==0) ? P.thal2d1 : P.thal2d2;
        const float* pa  = (r==0) ? P.alm2d1 : P.alm2d2;
        if (c < 520)       { v = -(float)P.mask[row*520+c] * rl(pd1[row*520+c]); }
        else if (c < 1040) { int cc=c-520;  v = -(float)P.mask[row*520+cc] * rl(pd2[row*520+cc]); }
        else if (c < 1196) { int cc=c-1040; v = -rl(pf[row*156+cc]); }
        else if (c < 1716) { int cc=c-1196; v =  rl(pt[row*520+cc]); }
        else               { int cc=c-1716; v = (cc<364) ? rl(pa[row*520+cc]) : 0.0f; }
        break;
      }
      case 2: {
        if (c < 156)       { v = -rl(P.fsi2fsi[row*156+c]); }
        else if (c < 676)  { int cc=c-156; v = rl(P.thal2fsi[row*520+cc]); }
        else if (c < 1196) { int cc=c-676; v = (cc<364) ? rl(P.alm2fsi[row*520+cc]) : 0.0f; }
        else               { int cc=c-1196; v = rl(P.iti2fsi[row*4+cc]); }
        break;
      }
      case 3: v = ((row<260)==(c<260)) ? -rl(P.d22gpe[row*520+c])  : 0.0f; break;
      case 4: v = ((row<260)==(c<260)) ? -rl(P.gpe2stn[row*520+c]) : 0.0f; break;
      case 5: {
        if (c < 520) { v = ((row<260)==(c<260)) ? -rl(P.d12snr[row*520+c]) : 0.0f; }
        else { int cc=c-520; v = ((row<260)==(cc<260)) ? rl(P.stn2snr[row*520+cc]) : 0.0f; }
        break;
      }
      case 6: v = ((row<260)==(c<260)) ? -rl(P.snr2thal[row*520+c]) : 0.0f; break;
      case 7: {
        if (c < 520) { v = rl(P.thal2alm[row*520+c]); }
        else { int cc=c-520; v = rl(P.alm2alm[row*520+cc]) * ((cc<364) ? 1.0f : -1.0f); }
        break;
      }
    }
    v *= AL;
  }
  Wt[e] = v;
}

// h is u-major: hT[u*8 + b] = hn[b*TOT + u]
__global__ void init_h(const float* __restrict__ hn, float* __restrict__ h0) {
  int i = blockIdx.x * blockDim.x + threadIdx.x;
  if (i < TOT * BB) {
    int u = i >> 3, b = i & 7;
    h0[i] = hn[b * TOT + u];
  }
}

__global__ void zero_bar(unsigned* __restrict__ bar) {
  if (threadIdx.x < 272) bar[threadIdx.x] = 0u;
}

__device__ __forceinline__ float2 agld2(const float* p) {
  unsigned long long v = __hip_atomic_load((const unsigned long long*)p,
                                           __ATOMIC_RELAXED, __HIP_MEMORY_SCOPE_AGENT);
  float2 r;
  r.x = __uint_as_float((unsigned)(v & 0xffffffffull));
  r.y = __uint_as_float((unsigned)(v >> 32));
  return r;
}
__device__ __forceinline__ void agst(float* p, float v) {
  __hip_atomic_store(p, v, __ATOMIC_RELAXED, __HIP_MEMORY_SCOPE_AGENT);
}

#define CF(W, HX) \
  acc[0][b] = fmaf((W).x, (HX), acc[0][b]); \
  acc[1][b] = fmaf((W).y, (HX), acc[1][b]); \
  acc[2][b] = fmaf((W).z, (HX), acc[2][b]); \
  acc[3][b] = fmaf((W).w, (HX), acc[3][b]);

// R4-exact register structure (w[9]=36 VGPR, acc[4][8]=32, scalar epilogue —
// the only proven no-spill config at the 1024-thread 64-VGPR cap).
// Only change: staged h layout [c][b] stride 9 -> inner reads are 8 ADJACENT
// dwords (compiler fuses to ds_read2_b32), staging writes 4 adjacent dwords
// (ds_write2_b32). Banks: addr=9c+b, consecutive c, gcd(9,32)=1 -> 2-way free.
__global__ void __launch_bounds__(1024, 4)
rnn_scan(const float* __restrict__ Wt, const float* __restrict__ noise,
         const float* __restrict__ inp, float* __restrict__ out,
         float* __restrict__ h0, float* __restrict__ h1,
         unsigned* __restrict__ bar) {
  __shared__ float S[33280];   // union: h [2304][9] (20736 f) / partials [128][260]
  const int bid = blockIdx.x, tid = threadIdx.x;
  int r = 0;
  while (bid >= kWgStart[r + 1]) ++r;

  unsigned* cnt1 = bar;          // 8 groups, stride 32 words (128B apart)
  unsigned* cnt0 = bar + 256;
  unsigned* flag = bar + 257;
  const int g8   = bid & 7;
  const unsigned gsz = (g8 == 0) ? 31u : 30u;

  const int wgl     = bid - kWgStart[r];
  const int cols    = kCols[r];
  const int rowcnt  = kRowCnt[r];
  const int rowbase = kRowBase[r];
  const int rg = tid >> 8, sp = tid & 255;
  const float* wtp = Wt + (size_t)kWtOff[r];
  const float ton = kTonic[r];
  const int l0 = kSegLen[r][0], l1 = kSegLen[r][1];
  const int g0 = kSegStart[r][0], g1 = kSegStart[r][1], g2 = kSegStart[r][2];

  // ---- W fragments: w[i] = quad-rows of col c = sp + 256*i  (36 VGPR)
  float4 w[9];
  {
    const int ug = wgl * 4 + rg;
    const float* wb = wtp + (size_t)ug * cols * 4;
    #pragma unroll
    for (int i = 0; i < 9; ++i) {
      int c = sp + (i << 8);
      w[i] = (c < cols) ? *(const float4*)(wb + (size_t)c * 4) : make_float4(0,0,0,0);
    }
  }

  // ---- staging tasks: task = c*2 + half (4608 tasks). Per task: 2 agld2
  // (unit g, batches half*4..+3) -> 4 adjacent LDS writes S[c*9 + half*4 + q].
  // pk = ((go+1)<<13) | task ; go=-1 => zero-fill ; pk=-1 => no task
  int pkk[5];
  #pragma unroll
  for (int k2 = 0; k2 < 5; ++k2) {
    int task = tid + (k2 << 10);
    if (task < 2 * CMAX) {
      int c = task >> 1;
      int half = task & 1;
      int go = -1;
      if (c < cols) {
        int g;
        if (c < l0)           g = g0 + c;
        else if (c < l0 + l1) g = g1 + (c - l0);
        else                  g = g2 + (c - l0 - l1);
        go = g * 8 + half * 4;
      }
      pkk[k2] = ((go + 1) << 13) | task;
    } else pkk[k2] = -1;
  }

  // ---- epilogue role (R4-exact): threads with (tid&7)==0 own o = tid>>3 = (row,b)
  const int  j     = tid & 7;
  const int  o     = tid >> 3;          // 0..127
  const int  erow  = o >> 3, eb = o & 7;
  const int  erowl = wgl * 16 + erow;
  const bool eiti  = (r == 2) && (wgl == 9) && (j == 0) && (erowl >= 156); // ITI fold
  const bool ewr   = (j == 0) && (erowl < rowcnt);
  const int  erg   = eiti ? (3796 + (erowl - 156)) : (rowbase + erowl);
  const bool own   = ewr || eiti;

  // prefetch step-0 epilogue operands; hp is carried thereafter (own row's output)
  float hp = 0.f, nz = 0.f, ii = 0.f;
  if (own) {
    hp = h0[erg * 8 + eb];
    nz = noise[((size_t)eb * TT) * TOT + erg];
    if (eiti) ii = inp[((size_t)eb * TT) * 4 + (erg - 3796)];
  }

  for (int t = 0; t < TT; ++t) {
    const float* __restrict__ hc = (t & 1) ? h1 : h0;
    float*       __restrict__ hx = (t & 1) ? h0 : h1;

    // ---- stage h: S[c*9 + b]  (2x b64 agent loads, 4 adjacent LDS writes)
    #pragma unroll
    for (int k2 = 0; k2 < 5; ++k2) {
      int pk = pkk[k2];
      if (pk >= 0) {
        int task = pk & 8191;
        int c    = task >> 1;
        int half = task & 1;
        int go   = (pk >> 13) - 1;
        float4 v = make_float4(0.f, 0.f, 0.f, 0.f);
        if (go >= 0) {
          float2 a  = agld2(hc + go);
          float2 b2 = agld2(hc + go + 2);
          v = make_float4(a.x, a.y, b2.x, b2.y);
        }
        int ds = c * 9 + half * 4;
        S[ds + 0] = v.x;
        S[ds + 1] = v.y;
        S[ds + 2] = v.z;
        S[ds + 3] = v.w;
      }
    }
    __syncthreads();

    // ---- FMA burst: 8 adjacent reads per col (ds_read2-fused), 288 fmaf
    float acc[4][8];
    #pragma unroll
    for (int r2 = 0; r2 < 4; ++r2)
      #pragma unroll
      for (int b = 0; b < 8; ++b) acc[r2][b] = 0.f;

    #pragma unroll
    for (int i = 0; i < 9; ++i) {
      const float4 wv = w[i];
      const int cb = (sp + (i << 8)) * 9;
      #pragma unroll
      for (int b = 0; b < 8; ++b) {
        const float h = S[cb + b];
        CF(wv, h)
      }
    }
    __syncthreads();   // done reading h; reuse S as partials

    // ---- partials (R4-exact): S[((rg*4+r2)*8+b)*260 + sp]
    #pragma unroll
    for (int r2 = 0; r2 < 4; ++r2)
      #pragma unroll
      for (int b = 0; b < 8; ++b)
        S[((rg * 4 + r2) * 8 + b) * 260 + sp] = acc[r2][b];
    __syncthreads();

    // ---- reduce (R4-exact): thread (o,j) sums sp = j+8k, then 3x shfl_xor
    float s = 0.f;
    #pragma unroll
    for (int k = 0; k < 32; ++k) s += S[o * 260 + j + (k << 3)];
    s += __shfl_xor(s, 1);
    s += __shfl_xor(s, 2);
    s += __shfl_xor(s, 4);

    float x = 0.f;
    if (eiti)     x = fmaxf(fmaf(0.9f, hp, AL * (nz + ii)), 0.0f);
    else if (ewr) x = fmaxf(fmaf(0.9f, hp, s + AL * (ton + nz)), 0.0f);
    if (own) agst(&hx[erg * 8 + eb], x);   // LLC-coherent store
    __syncthreads();   // drain hx stores (vmcnt(0) before s_barrier)

    // ---- arrive (release: all WG stores LLC-acked before the count)
    if (tid == 0) {
      unsigned old = atomicAdd(&cnt1[g8 * 32], 1u);
      if (old + 1 == gsz * (unsigned)(t + 1)) {
        unsigned o0 = atomicAdd(cnt0, 1u);
        if (o0 + 1 == 8u * (unsigned)(t + 1)) {
          __hip_atomic_store(flag, (unsigned)(t + 1), __ATOMIC_RELAXED, __HIP_MEMORY_SCOPE_AGENT);
        }
      }
    }

    // ---- independent work hidden under the barrier: out-store + t+1 prefetch
    if (own) {
      out[((size_t)eb * TT + t) * TOT + erg] = x;
      hp = x;                               // own row's h_prev for t+1
      if (t + 1 < TT) {
        nz = noise[((size_t)eb * TT + (t + 1)) * TOT + erg];
        if (eiti) ii = inp[((size_t)eb * TT + (t + 1)) * 4 + (erg - 3796)];
      }
    }

    // ---- wait
    if (tid == 0) {
      while (__hip_atomic_load(flag, __ATOMIC_RELAXED, __HIP_MEMORY_SCOPE_AGENT) < (unsigned)(t + 1)) {}
    }
    __syncthreads();
  }
}

extern "C" void kernel_launch(void* const* d_in, const int* in_sizes, int n_in,
                              void* d_out, int out_size, void* d_ws, size_t ws_size,
                              hipStream_t stream) {
  Params P;
  P.d12d1   = (const float*)d_in[0];  P.d22d2   = (const float*)d_in[1];
  P.d12d2   = (const float*)d_in[2];  P.d22d1   = (const float*)d_in[3];
  P.thal2alm= (const float*)d_in[4];  P.thal2d1 = (const float*)d_in[5];
  P.thal2d2 = (const float*)d_in[6];  P.alm2alm = (const float*)d_in[7];
  P.alm2d1  = (const float*)d_in[8];  P.alm2d2  = (const float*)d_in[9];
  P.d12snr  = (const float*)d_in[10]; P.d22gpe  = (const float*)d_in[11];
  P.gpe2stn = (const float*)d_in[12]; P.stn2snr = (const float*)d_in[13];
  P.snr2thal= (const float*)d_in[14]; P.fsi2d1  = (const float*)d_in[15];
  P.fsi2d2  = (const float*)d_in[16]; P.thal2fsi= (const float*)d_in[17];
  P.alm2fsi = (const float*)d_in[18]; P.iti2fsi = (const float*)d_in[19];
  P.fsi2fsi = (const float*)d_in[20]; P.mask    = (const int*)d_in[21];
  const float* inp   = (const float*)d_in[22];
  const float* hn    = (const float*)d_in[23];
  const float* noise = (const float*)d_in[24];

  float* ws = (float*)d_ws;
  float* Wt = ws;
  float* h0 = ws + WT_FLOATS;
  float* h1 = h0 + TOT * BB;
  unsigned* bar = (unsigned*)(h1 + TOT * BB);

  hipLaunchKernelGGL(prep_wt,  dim3((WT_FLOATS + 255) / 256), dim3(256), 0, stream, P, Wt);
  hipLaunchKernelGGL(init_h,   dim3((TOT * BB + 255) / 256),  dim3(256), 0, stream, hn, h0);
  hipLaunchKernelGGL(zero_bar, dim3(1), dim3(512), 0, stream, bar);

  const float* WtA = Wt; const float* noiseA = noise; const float* inpA = inp;
  float* outA = (float*)d_out; float* h0A = h0; float* h1A = h1; unsigned* barA = bar;
  void* kargs[7] = {&WtA, &noiseA, &inpA, &outA, &h0A, &h1A, &barA};
  hipLaunchCooperativeKernel((const void*)rnn_scan, dim3(NWG), dim3(1024), kargs, 0, stream);
}

// Round 12
// 6861.621 us; speedup vs baseline: 3.4566x; 1.1306x over previous
//
#include <hip/hip_runtime.h>

#define TOT   3800
#define BB    8
#define TT    1000
#define AL    0.1f

constexpr int WT_FLOATS = 4475136;   // sum of padded region blocks
constexpr int NWG       = 241;       // ITI folded into FSI wg 9's padded rows
constexpr int CMAX      = 2304;      // padded packed-col count

// region order: D1, D2, FSI(+ITI), GPE, STN, SNR, THAL, ALM
__constant__ int   kWgStart[9]    = {0,33,66,76,109,142,175,208,241};
__constant__ int   kRowBase[8]    = {0,520,1040,1196,1716,2236,2756,3276};
__constant__ int   kRowCnt[8]     = {520,520,156,520,520,520,520,520};
__constant__ int   kCols[8]       = {2236,2236,1200,520,520,1040,520,1040};
__constant__ int   kWtOff[8]      = {0,1180608,2361216,2553216,2827776,3102336,3651456,3926016};
__constant__ int   kWtEnd[8]      = {1180608,2361216,2553216,2827776,3102336,3651456,3926016,4475136};
__constant__ float kTonic[8]      = {0.01f,0.01f,0.01f,0.8f,0.6f,0.8f,0.01f,0.01f};
// staging segments: packed col -> global h unit index
__constant__ int   kSegStart[8][3]= {{0,2756,0},{0,2756,0},{1040,2756,3796},{520,0,0},{1196,0,0},{0,1716,0},{2236,0,0},{2756,0,0}};
__constant__ int   kSegLen[8][3]  = {{1196,1040,0},{1196,1040,0},{156,1040,4},{520,0,0},{520,0,0},{520,520,0},{520,0,0},{1040,0,0}};

struct Params {
  const float *d12d1,*d22d2,*d12d2,*d22d1,*thal2alm,*thal2d1,*thal2d2,*alm2alm,
              *alm2d1,*alm2d2,*d12snr,*d22gpe,*gpe2stn,*stn2snr,*snr2thal,
              *fsi2d1,*fsi2d2,*thal2fsi,*alm2fsi,*iti2fsi,*fsi2fsi;
  const int* mask;
};

__device__ __forceinline__ float rl(float x) { return fmaxf(x, 0.0f); }

// Build packed, pre-masked, pre-signed, ALPHA-scaled W.
// Layout per region: offset = (ugg*cols + col)*4 + j, row = ugg*4 + j
__global__ void prep_wt(Params P, float* __restrict__ Wt) {
  int e = blockIdx.x * blockDim.x + threadIdx.x;
  if (e >= WT_FLOATS) return;
  int r = 0;
  while (e >= kWtEnd[r]) ++r;
  int base  = (r == 0) ? 0 : kWtEnd[r-1];
  int local = e - base;
  int j    = local & 3;
  int q    = local >> 2;
  int cols = kCols[r];
  int col  = q % cols;
  int ugg  = q / cols;
  int row  = ugg * 4 + j;
  float v = 0.0f;
  if (row < kRowCnt[r]) {
    int c = col;
    switch (r) {
      case 0: case 1: {
        const float* pd1 = (r==0) ? P.d12d1 : P.d12d2;
        const float* pd2 = (r==0) ? P.d22d1 : P.d22d2;
        const float* pf  = (r==0) ? P.fsi2d1 : P.fsi2d2;
        const float* pt  = (r==0) ? P.thal2d1 : P.thal2d2;
        const float* pa  = (r==0) ? P.alm2d1 : P.alm2d2;
        if (c < 520)       { v = -(float)P.mask[row*520+c] * rl(pd1[row*520+c]); }
        else if (c < 1040) { int cc=c-520;  v = -(float)P.mask[row*520+cc] * rl(pd2[row*520+cc]); }
        else if (c < 1196) { int cc=c-1040; v = -rl(pf[row*156+cc]); }
        else if (c < 1716) { int cc=c-1196; v =  rl(pt[row*520+cc]); }
        else               { int cc=c-1716; v = (cc<364) ? rl(pa[row*520+cc]) : 0.0f; }
        break;
      }
      case 2: {
        if (c < 156)       { v = -rl(P.fsi2fsi[row*156+c]); }
        else if (c < 676)  { int cc=c-156; v = rl(P.thal2fsi[row*520+cc]); }
        else if (c < 1196) { int cc=c-676; v = (cc<364) ? rl(P.alm2fsi[row*520+cc]) : 0.0f; }
        else               { int cc=c-1196; v = rl(P.iti2fsi[row*4+cc]); }
        break;
      }
      case 3: v = ((row<260)==(c<260)) ? -rl(P.d22gpe[row*520+c])  : 0.0f; break;
      case 4: v = ((row<260)==(c<260)) ? -rl(P.gpe2stn[row*520+c]) : 0.0f; break;
      case 5: {
        if (c < 520) { v = ((row<260)==(c<260)) ? -rl(P.d12snr[row*520+c]) : 0.0f; }
        else { int cc=c-520; v = ((row<260)==(cc<260)) ? rl(P.stn2snr[row*520+cc]) : 0.0f; }
        break;
      }
      case 6: v = ((row<260)==(c<260)) ? -rl(P.snr2thal[row*520+c]) : 0.0f; break;
      case 7: {
        if (c < 520) { v = rl(P.thal2alm[row*520+c]); }
        else { int cc=c-520; v = rl(P.alm2alm[row*520+cc]) * ((cc<364) ? 1.0f : -1.0f); }
        break;
      }
    }
    v *= AL;
  }
  Wt[e] = v;
}

// h is u-major: hT[u*8 + b] = hn[b*TOT + u]
__global__ void init_h(const float* __restrict__ hn, float* __restrict__ h0) {
  int i = blockIdx.x * blockDim.x + threadIdx.x;
  if (i < TOT * BB) {
    int u = i >> 3, b = i & 7;
    h0[i] = hn[b * TOT + u];
  }
}

__global__ void zero_bar(unsigned* __restrict__ bar) {
  if (threadIdx.x < 272) bar[threadIdx.x] = 0u;
}

__device__ __forceinline__ void agst(float* p, float v) {
  __hip_atomic_store(p, v, __ATOMIC_RELAXED, __HIP_MEMORY_SCOPE_AGENT);
}

#define CF(W, HX) \
  acc[0][b] = fmaf((W).x, (HX), acc[0][b]); \
  acc[1][b] = fmaf((W).y, (HX), acc[1][b]); \
  acc[2][b] = fmaf((W).z, (HX), acc[2][b]); \
  acc[3][b] = fmaf((W).w, (HX), acc[3][b]);

// R11 structure (proven no-spill: w[9]=36 VGPR, acc[4][8]=32, scalar epilogue,
// h in LDS as [c][b] stride 9 -> ds_read2-fused inner reads).
// R12 deltas: (1) barrier pollers spin on cnt0 (flag hop removed);
// (2) staging uses one global_load_dwordx4 sc0 sc1 per task (issue-all,
//     single vmcnt(0), then LDS writes) -- halves LLC request count.
__global__ void __launch_bounds__(1024, 4)
rnn_scan(const float* __restrict__ Wt, const float* __restrict__ noise,
         const float* __restrict__ inp, float* __restrict__ out,
         float* __restrict__ h0, float* __restrict__ h1,
         unsigned* __restrict__ bar) {
  __shared__ float S[33280];   // union: h [2304][9] (20736 f) / partials [128][260]
  const int bid = blockIdx.x, tid = threadIdx.x;
  int r = 0;
  while (bid >= kWgStart[r + 1]) ++r;

  unsigned* cnt1 = bar;          // 8 groups, stride 32 words (128B apart)
  unsigned* cnt0 = bar + 256;
  const int g8   = bid & 7;
  const unsigned gsz = (g8 == 0) ? 31u : 30u;

  const int wgl     = bid - kWgStart[r];
  const int cols    = kCols[r];
  const int rowcnt  = kRowCnt[r];
  const int rowbase = kRowBase[r];
  const int rg = tid >> 8, sp = tid & 255;
  const float* wtp = Wt + (size_t)kWtOff[r];
  const float ton = kTonic[r];
  const int l0 = kSegLen[r][0], l1 = kSegLen[r][1];
  const int g0 = kSegStart[r][0], g1 = kSegStart[r][1], g2 = kSegStart[r][2];

  // ---- W fragments: w[i] = quad-rows of col c = sp + 256*i  (36 VGPR)
  float4 w[9];
  {
    const int ug = wgl * 4 + rg;
    const float* wb = wtp + (size_t)ug * cols * 4;
    #pragma unroll
    for (int i = 0; i < 9; ++i) {
      int c = sp + (i << 8);
      w[i] = (c < cols) ? *(const float4*)(wb + (size_t)c * 4) : make_float4(0,0,0,0);
    }
  }

  // ---- staging tasks: task = c*2 + half (4608 tasks). Per task: 1 b128
  // agent load (unit g, batches half*4..+3) -> 4 adjacent LDS writes.
  // pk = ((go+1)<<13) | task ; go=-1 => zero-fill ; pk=-1 => no task
  int pkk[5];
  #pragma unroll
  for (int k2 = 0; k2 < 5; ++k2) {
    int task = tid + (k2 << 10);
    if (task < 2 * CMAX) {
      int c = task >> 1;
      int half = task & 1;
      int go = -1;
      if (c < cols) {
        int g;
        if (c < l0)           g = g0 + c;
        else if (c < l0 + l1) g = g1 + (c - l0);
        else                  g = g2 + (c - l0 - l1);
        go = g * 8 + half * 4;     // 16B-aligned element offset
      }
      pkk[k2] = ((go + 1) << 13) | task;
    } else pkk[k2] = -1;
  }

  // ---- epilogue role (R4-exact): threads with (tid&7)==0 own o = tid>>3 = (row,b)
  const int  j     = tid & 7;
  const int  o     = tid >> 3;          // 0..127
  const int  erow  = o >> 3, eb = o & 7;
  const int  erowl = wgl * 16 + erow;
  const bool eiti  = (r == 2) && (wgl == 9) && (j == 0) && (erowl >= 156); // ITI fold
  const bool ewr   = (j == 0) && (erowl < rowcnt);
  const int  erg   = eiti ? (3796 + (erowl - 156)) : (rowbase + erowl);
  const bool own   = ewr || eiti;

  // prefetch step-0 epilogue operands; hp is carried thereafter (own row's output)
  float hp = 0.f, nz = 0.f, ii = 0.f;
  if (own) {
    hp = h0[erg * 8 + eb];
    nz = noise[((size_t)eb * TT) * TOT + erg];
    if (eiti) ii = inp[((size_t)eb * TT) * 4 + (erg - 3796)];
  }

  for (int t = 0; t < TT; ++t) {
    const float* __restrict__ hc = (t & 1) ? h1 : h0;
    float*       __restrict__ hx = (t & 1) ? h0 : h1;

    // ---- stage h: issue all b128 agent loads, single vmcnt, write to LDS
    float4 vv[5];
    #pragma unroll
    for (int k2 = 0; k2 < 5; ++k2) {
      int pk = pkk[k2];
      if (pk >= 0) {
        int go = (pk >> 13) - 1;
        if (go >= 0) {
          const float* p = hc + go;
          asm volatile("global_load_dwordx4 %0, %1, off sc0 sc1"
                       : "=v"(vv[k2]) : "v"(p));
        } else {
          vv[k2] = make_float4(0.f, 0.f, 0.f, 0.f);
        }
      }
    }
    asm volatile("s_waitcnt vmcnt(0)" ::: "memory");
    #pragma unroll
    for (int k2 = 0; k2 < 5; ++k2) {
      int pk = pkk[k2];
      if (pk >= 0) {
        int task = pk & 8191;
        int c    = task >> 1;
        int half = task & 1;
        int ds   = c * 9 + half * 4;
        S[ds + 0] = vv[k2].x;
        S[ds + 1] = vv[k2].y;
        S[ds + 2] = vv[k2].z;
        S[ds + 3] = vv[k2].w;
      }
    }
    __syncthreads();

    // ---- FMA burst: 8 adjacent reads per col (ds_read2-fused), 288 fmaf
    float acc[4][8];
    #pragma unroll
    for (int r2 = 0; r2 < 4; ++r2)
      #pragma unroll
      for (int b = 0; b < 8; ++b) acc[r2][b] = 0.f;

    #pragma unroll
    for (int i = 0; i < 9; ++i) {
      const float4 wv = w[i];
      const int cb = (sp + (i << 8)) * 9;
      #pragma unroll
      for (int b = 0; b < 8; ++b) {
        const float h = S[cb + b];
        CF(wv, h)
      }
    }
    __syncthreads();   // done reading h; reuse S as partials

    // ---- partials (R4-exact): S[((rg*4+r2)*8+b)*260 + sp]
    #pragma unroll
    for (int r2 = 0; r2 < 4; ++r2)
      #pragma unroll
      for (int b = 0; b < 8; ++b)
        S[((rg * 4 + r2) * 8 + b) * 260 + sp] = acc[r2][b];
    __syncthreads();

    // ---- reduce (R4-exact): thread (o,j) sums sp = j+8k, then 3x shfl_xor
    float s = 0.f;
    #pragma unroll
    for (int k = 0; k < 32; ++k) s += S[o * 260 + j + (k << 3)];
    s += __shfl_xor(s, 1);
    s += __shfl_xor(s, 2);
    s += __shfl_xor(s, 4);

    float x = 0.f;
    if (eiti)     x = fmaxf(fmaf(0.9f, hp, AL * (nz + ii)), 0.0f);
    else if (ewr) x = fmaxf(fmaf(0.9f, hp, s + AL * (ton + nz)), 0.0f);
    if (own) agst(&hx[erg * 8 + eb], x);   // LLC-coherent store
    __syncthreads();   // drain hx stores (vmcnt(0) before s_barrier)

    // ---- arrive: 2-level, release through LLC (stores acked at sync above)
    if (tid == 0) {
      unsigned old = atomicAdd(&cnt1[g8 * 32], 1u);
      if (old + 1 == gsz * (unsigned)(t + 1)) {
        atomicAdd(cnt0, 1u);     // 8th add for step t makes cnt0 == 8*(t+1)
      }
    }

    // ---- independent work hidden under the barrier: out-store + t+1 prefetch
    if (own) {
      out[((size_t)eb * TT + t) * TOT + erg] = x;
      hp = x;                               // own row's h_prev for t+1
      if (t + 1 < TT) {
        nz = noise[((size_t)eb * TT + (t + 1)) * TOT + erg];
        if (eiti) ii = inp[((size_t)eb * TT + (t + 1)) * 4 + (erg - 3796)];
      }
    }

    // ---- wait: poll cnt0 directly (one fewer LLC hop than flag design)
    if (tid == 0) {
      while (__hip_atomic_load(cnt0, __ATOMIC_RELAXED, __HIP_MEMORY_SCOPE_AGENT)
             < 8u * (unsigned)(t + 1)) {}
    }
    __syncthreads();
  }
}

extern "C" void kernel_launch(void* const* d_in, const int* in_sizes, int n_in,
                              void* d_out, int out_size, void* d_ws, size_t ws_size,
                              hipStream_t stream) {
  Params P;
  P.d12d1   = (const float*)d_in[0];  P.d22d2   = (const float*)d_in[1];
  P.d12d2   = (const float*)d_in[2];  P.d22d1   = (const float*)d_in[3];
  P.thal2alm= (const float*)d_in[4];  P.thal2d1 = (const float*)d_in[5];
  P.thal2d2 = (const float*)d_in[6];  P.alm2alm = (const float*)d_in[7];
  P.alm2d1  = (const float*)d_in[8];  P.alm2d2  = (const float*)d_in[9];
  P.d12snr  = (const float*)d_in[10]; P.d22gpe  = (const float*)d_in[11];
  P.gpe2stn = (const float*)d_in[12]; P.stn2snr = (const float*)d_in[13];
  P.snr2thal= (const float*)d_in[14]; P.fsi2d1  = (const float*)d_in[15];
  P.fsi2d2  = (const float*)d_in[16]; P.thal2fsi= (const float*)d_in[17];
  P.alm2fsi = (const float*)d_in[18]; P.iti2fsi = (const float*)d_in[19];
  P.fsi2fsi = (const float*)d_in[20]; P.mask    = (const int*)d_in[21];
  const float* inp   = (const float*)d_in[22];
  const float* hn    = (const float*)d_in[23];
  const float* noise = (const float*)d_in[24];

  float* ws = (float*)d_ws;
  float* Wt = ws;
  float* h0 = ws + WT_FLOATS;
  float* h1 = h0 + TOT * BB;
  unsigned* bar = (unsigned*)(h1 + TOT * BB);

  hipLaunchKernelGGL(prep_wt,  dim3((WT_FLOATS + 255) / 256), dim3(256), 0, stream, P, Wt);
  hipLaunchKernelGGL(init_h,   dim3((TOT * BB + 255) / 256),  dim3(256), 0, stream, hn, h0);
  hipLaunchKernelGGL(zero_bar, dim3(1), dim3(512), 0, stream, bar);

  const float* WtA = Wt; const float* noiseA = noise; const float* inpA = inp;
  float* outA = (float*)d_out; float* h0A = h0; float* h1A = h1; unsigned* barA = bar;
  void* kargs[7] = {&WtA, &noiseA, &inpA, &outA, &h0A, &h1A, &barA};
  hipLaunchCooperativeKernel((const void*)rnn_scan, dim3(NWG), dim3(1024), kargs, 0, stream);
}

// Round 14
// 6408.614 us; speedup vs baseline: 3.7010x; 1.0707x over previous
//
#include <hip/hip_runtime.h>

#define TOT   3800
#define BB    8
#define TT    1000
#define AL    0.1f

constexpr int WT_FLOATS = 4475136;   // sum of padded region blocks
constexpr int NWG       = 241;       // ITI folded into FSI wg 9's padded rows
constexpr int CMAX      = 2304;      // padded packed-col count

// region order: D1, D2, FSI(+ITI), GPE, STN, SNR, THAL, ALM
__constant__ int   kWgStart[9]    = {0,33,66,76,109,142,175,208,241};
__constant__ int   kRowBase[8]    = {0,520,1040,1196,1716,2236,2756,3276};
__constant__ int   kRowCnt[8]     = {520,520,156,520,520,520,520,520};
__constant__ int   kCols[8]       = {2236,2236,1200,520,520,1040,520,1040};
__constant__ int   kWtOff[8]      = {0,1180608,2361216,2553216,2827776,3102336,3651456,3926016};
__constant__ int   kWtEnd[8]      = {1180608,2361216,2553216,2827776,3102336,3651456,3926016,4475136};
__constant__ float kTonic[8]      = {0.01f,0.01f,0.01f,0.8f,0.6f,0.8f,0.01f,0.01f};
// staging segments: packed col -> global h unit index
__constant__ int   kSegStart[8][3]= {{0,2756,0},{0,2756,0},{1040,2756,3796},{520,0,0},{1196,0,0},{0,1716,0},{2236,0,0},{2756,0,0}};
__constant__ int   kSegLen[8][3]  = {{1196,1040,0},{1196,1040,0},{156,1040,4},{520,0,0},{520,0,0},{520,520,0},{520,0,0},{1040,0,0}};

struct Params {
  const float *d12d1,*d22d2,*d12d2,*d22d1,*thal2alm,*thal2d1,*thal2d2,*alm2alm,
              *alm2d1,*alm2d2,*d12snr,*d22gpe,*gpe2stn,*stn2snr,*snr2thal,
              *fsi2d1,*fsi2d2,*thal2fsi,*alm2fsi,*iti2fsi,*fsi2fsi;
  const int* mask;
};

__device__ __forceinline__ float rl(float x) { return fmaxf(x, 0.0f); }

// Build packed, pre-masked, pre-signed, ALPHA-scaled W.
// Layout per region: offset = (ugg*cols + col)*4 + j, row = ugg*4 + j
__global__ void prep_wt(Params P, float* __restrict__ Wt) {
  int e = blockIdx.x * blockDim.x + threadIdx.x;
  if (e >= WT_FLOATS) return;
  int r = 0;
  while (e >= kWtEnd[r]) ++r;
  int base  = (r == 0) ? 0 : kWtEnd[r-1];
  int local = e - base;
  int j    = local & 3;
  int q    = local >> 2;
  int cols = kCols[r];
  int col  = q % cols;
  int ugg  = q / cols;
  int row  = ugg * 4 + j;
  float v = 0.0f;
  if (row < kRowCnt[r]) {
    int c = col;
    switch (r) {
      case 0: case 1: {
        const float* pd1 = (r==0) ? P.d12d1 : P.d12d2;
        const float* pd2 = (r==0) ? P.d22d1 : P.d22d2;
        const float* pf  = (r==0) ? P.fsi2d1 : P.fsi2d2;
        const float* pt  = (r==0) ? P.thal2d1 : P.thal2d2;
        const float* pa  = (r==0) ? P.alm2d1 : P.alm2d2;
        if (c < 520)       { v = -(float)P.mask[row*520+c] * rl(pd1[row*520+c]); }
        else if (c < 1040) { int cc=c-520;  v = -(float)P.mask[row*520+cc] * rl(pd2[row*520+cc]); }
        else if (c < 1196) { int cc=c-1040; v = -rl(pf[row*156+cc]); }
        else if (c < 1716) { int cc=c-1196; v =  rl(pt[row*520+cc]); }
        else               { int cc=c-1716; v = (cc<364) ? rl(pa[row*520+cc]) : 0.0f; }
        break;
      }
      case 2: {
        if (c < 156)       { v = -rl(P.fsi2fsi[row*156+c]); }
        else if (c < 676)  { int cc=c-156; v = rl(P.thal2fsi[row*520+cc]); }
        else if (c < 1196) { int cc=c-676; v = (cc<364) ? rl(P.alm2fsi[row*520+cc]) : 0.0f; }
        else               { int cc=c-1196; v = rl(P.iti2fsi[row*4+cc]); }
        break;
      }
      case 3: v = ((row<260)==(c<260)) ? -rl(P.d22gpe[row*520+c])  : 0.0f; break;
      case 4: v = ((row<260)==(c<260)) ? -rl(P.gpe2stn[row*520+c]) : 0.0f; break;
      case 5: {
        if (c < 520) { v = ((row<260)==(c<260)) ? -rl(P.d12snr[row*520+c]) : 0.0f; }
        else { int cc=c-520; v = ((row<260)==(cc<260)) ? rl(P.stn2snr[row*520+cc]) : 0.0f; }
        break;
      }
      case 6: v = ((row<260)==(c<260)) ? -rl(P.snr2thal[row*520+c]) : 0.0f; break;
      case 7: {
        if (c < 520) { v = rl(P.thal2alm[row*520+c]); }
        else { int cc=c-520; v = rl(P.alm2alm[row*520+cc]) * ((cc<364) ? 1.0f : -1.0f); }
        break;
      }
    }
    v *= AL;
  }
  Wt[e] = v;
}

// h is u-major: hT[u*8 + b] = hn[b*TOT + u]
__global__ void init_h(const float* __restrict__ hn, float* __restrict__ h0) {
  int i = blockIdx.x * blockDim.x + threadIdx.x;
  if (i < TOT * BB) {
    int u = i >> 3, b = i & 7;
    h0[i] = hn[b * TOT + u];
  }
}

__global__ void zero_bar(unsigned* __restrict__ bar) {
  if (threadIdx.x < 272) bar[threadIdx.x] = 0u;
}

__device__ __forceinline__ void agst(float* p, float v) {
  __hip_atomic_store(p, v, __ATOMIC_RELAXED, __HIP_MEMORY_SCOPE_AGENT);
}

#define CF(W, HX) \
  acc[0][b] = fmaf((W).x, (HX), acc[0][b]); \
  acc[1][b] = fmaf((W).y, (HX), acc[1][b]); \
  acc[2][b] = fmaf((W).z, (HX), acc[2][b]); \
  acc[3][b] = fmaf((W).w, (HX), acc[3][b]);

// R12 structure (proven no-spill: w[9]=36 VGPR, acc[4][8]=32, scalar epilogue,
// h in LDS [c][b], b128 staging loads, cnt0-poll barrier, R4-exact partials).
// R14 delta (address-only): h stride 9 -> 12. c*12+half*4 is 16B-aligned, so
// the 4 adjacent staging stores and 8 adjacent FMA reads are b128-fusable.
// Banks: b128 quad base 12sp%32 = {0,12,24,4,16,28,8,20} tiles all banks.
__global__ void __launch_bounds__(1024, 4)
rnn_scan(const float* __restrict__ Wt, const float* __restrict__ noise,
         const float* __restrict__ inp, float* __restrict__ out,
         float* __restrict__ h0, float* __restrict__ h1,
         unsigned* __restrict__ bar) {
  __shared__ float S[33280];   // union: h [2304][12] (27648 f) / partials [128][260]
  const int bid = blockIdx.x, tid = threadIdx.x;
  int r = 0;
  while (bid >= kWgStart[r + 1]) ++r;

  unsigned* cnt1 = bar;          // 8 groups, stride 32 words (128B apart)
  unsigned* cnt0 = bar + 256;
  const int g8   = bid & 7;
  const unsigned gsz = (g8 == 0) ? 31u : 30u;

  const int wgl     = bid - kWgStart[r];
  const int cols    = kCols[r];
  const int rowcnt  = kRowCnt[r];
  const int rowbase = kRowBase[r];
  const int rg = tid >> 8, sp = tid & 255;
  const float* wtp = Wt + (size_t)kWtOff[r];
  const float ton = kTonic[r];
  const int l0 = kSegLen[r][0], l1 = kSegLen[r][1];
  const int g0 = kSegStart[r][0], g1 = kSegStart[r][1], g2 = kSegStart[r][2];

  // ---- W fragments: w[i] = quad-rows of col c = sp + 256*i  (36 VGPR)
  float4 w[9];
  {
    const int ug = wgl * 4 + rg;
    const float* wb = wtp + (size_t)ug * cols * 4;
    #pragma unroll
    for (int i = 0; i < 9; ++i) {
      int c = sp + (i << 8);
      w[i] = (c < cols) ? *(const float4*)(wb + (size_t)c * 4) : make_float4(0,0,0,0);
    }
  }

  // ---- staging tasks: task = c*2 + half (4608 tasks). Per task: 1 b128
  // agent load (unit g, batches half*4..+3) -> 4 adjacent LDS writes.
  // pk = ((go+1)<<13) | task ; go=-1 => zero-fill ; pk=-1 => no task
  int pkk[5];
  #pragma unroll
  for (int k2 = 0; k2 < 5; ++k2) {
    int task = tid + (k2 << 10);
    if (task < 2 * CMAX) {
      int c = task >> 1;
      int half = task & 1;
      int go = -1;
      if (c < cols) {
        int g;
        if (c < l0)           g = g0 + c;
        else if (c < l0 + l1) g = g1 + (c - l0);
        else                  g = g2 + (c - l0 - l1);
        go = g * 8 + half * 4;     // 16B-aligned element offset
      }
      pkk[k2] = ((go + 1) << 13) | task;
    } else pkk[k2] = -1;
  }

  // ---- epilogue role (R4-exact): threads with (tid&7)==0 own o = tid>>3 = (row,b)
  const int  j     = tid & 7;
  const int  o     = tid >> 3;          // 0..127  (= row16*8 + b)
  const int  erow  = o >> 3, eb = o & 7;
  const int  erowl = wgl * 16 + erow;
  const bool eiti  = (r == 2) && (wgl == 9) && (j == 0) && (erowl >= 156); // ITI fold
  const bool ewr   = (j == 0) && (erowl < rowcnt);
  const int  erg   = eiti ? (3796 + (erowl - 156)) : (rowbase + erowl);
  const bool own   = ewr || eiti;

  // prefetch step-0 epilogue operands; hp is carried thereafter (own row's output)
  float hp = 0.f, nz = 0.f, ii = 0.f;
  if (own) {
    hp = h0[erg * 8 + eb];
    nz = noise[((size_t)eb * TT) * TOT + erg];
    if (eiti) ii = inp[((size_t)eb * TT) * 4 + (erg - 3796)];
  }

  for (int t = 0; t < TT; ++t) {
    const float* __restrict__ hc = (t & 1) ? h1 : h0;
    float*       __restrict__ hx = (t & 1) ? h0 : h1;

    // ---- stage h: issue all b128 agent loads, single vmcnt, write to LDS
    float4 vv[5];
    #pragma unroll
    for (int k2 = 0; k2 < 5; ++k2) {
      int pk = pkk[k2];
      if (pk >= 0) {
        int go = (pk >> 13) - 1;
        if (go >= 0) {
          const float* p = hc + go;
          asm volatile("global_load_dwordx4 %0, %1, off sc0 sc1"
                       : "=v"(vv[k2]) : "v"(p));
        } else {
          vv[k2] = make_float4(0.f, 0.f, 0.f, 0.f);
        }
      }
    }
    asm volatile("s_waitcnt vmcnt(0)" ::: "memory");
    #pragma unroll
    for (int k2 = 0; k2 < 5; ++k2) {
      int pk = pkk[k2];
      if (pk >= 0) {
        int task = pk & 8191;
        int c    = task >> 1;
        int half = task & 1;
        int ds   = c * 12 + half * 4;   // 16B-aligned -> b128-fusable
        S[ds + 0] = vv[k2].x;
        S[ds + 1] = vv[k2].y;
        S[ds + 2] = vv[k2].z;
        S[ds + 3] = vv[k2].w;
      }
    }
    __syncthreads();

    // ---- FMA burst: 8 adjacent reads per col (b128/read2-fusable), 288 fmaf
    float acc[4][8];
    #pragma unroll
    for (int r2 = 0; r2 < 4; ++r2)
      #pragma unroll
      for (int b = 0; b < 8; ++b) acc[r2][b] = 0.f;

    #pragma unroll
    for (int i = 0; i < 9; ++i) {
      const float4 wv = w[i];
      const int cb = (sp + (i << 8)) * 12;
      #pragma unroll
      for (int b = 0; b < 8; ++b) {
        const float h = S[cb + b];
        CF(wv, h)
      }
    }
    __syncthreads();   // done reading h; reuse S as partials

    // ---- partials (R4-exact): S[((rg*4+r2)*8+b)*260 + sp]
    #pragma unroll
    for (int r2 = 0; r2 < 4; ++r2)
      #pragma unroll
      for (int b = 0; b < 8; ++b)
        S[((rg * 4 + r2) * 8 + b) * 260 + sp] = acc[r2][b];
    __syncthreads();

    // ---- reduce (R4-exact): thread (o,j) sums sp = j+8k, then 3x shfl_xor
    float s = 0.f;
    #pragma unroll
    for (int k = 0; k < 32; ++k) s += S[o * 260 + j + (k << 3)];
    s += __shfl_xor(s, 1);
    s += __shfl_xor(s, 2);
    s += __shfl_xor(s, 4);

    float x = 0.f;
    if (eiti)     x = fmaxf(fmaf(0.9f, hp, AL * (nz + ii)), 0.0f);
    else if (ewr) x = fmaxf(fmaf(0.9f, hp, s + AL * (ton + nz)), 0.0f);
    if (own) agst(&hx[erg * 8 + eb], x);   // LLC-coherent store
    __syncthreads();   // drain hx stores (vmcnt(0) before s_barrier)

    // ---- arrive: 2-level, release through LLC (stores acked at sync above)
    if (tid == 0) {
      unsigned old = atomicAdd(&cnt1[g8 * 32], 1u);
      if (old + 1 == gsz * (unsigned)(t + 1)) {
        atomicAdd(cnt0, 1u);     // 8th add for step t makes cnt0 == 8*(t+1)
      }
    }

    // ---- independent work hidden under the barrier: out-store + t+1 prefetch
    if (own) {
      out[((size_t)eb * TT + t) * TOT + erg] = x;
      hp = x;                               // own row's h_prev for t+1
      if (t + 1 < TT) {
        nz = noise[((size_t)eb * TT + (t + 1)) * TOT + erg];
        if (eiti) ii = inp[((size_t)eb * TT + (t + 1)) * 4 + (erg - 3796)];
      }
    }

    // ---- wait: poll cnt0 directly
    if (tid == 0) {
      while (__hip_atomic_load(cnt0, __ATOMIC_RELAXED, __HIP_MEMORY_SCOPE_AGENT)
             < 8u * (unsigned)(t + 1)) {}
    }
    __syncthreads();
  }
}

extern "C" void kernel_launch(void* const* d_in, const int* in_sizes, int n_in,
                              void* d_out, int out_size, void* d_ws, size_t ws_size,
                              hipStream_t stream) {
  Params P;
  P.d12d1   = (const float*)d_in[0];  P.d22d2   = (const float*)d_in[1];
  P.d12d2   = (const float*)d_in[2];  P.d22d1   = (const float*)d_in[3];
  P.thal2alm= (const float*)d_in[4];  P.thal2d1 = (const float*)d_in[5];
  P.thal2d2 = (const float*)d_in[6];  P.alm2alm = (const float*)d_in[7];
  P.alm2d1  = (const float*)d_in[8];  P.alm2d2  = (const float*)d_in[9];
  P.d12snr  = (const float*)d_in[10]; P.d22gpe  = (const float*)d_in[11];
  P.gpe2stn = (const float*)d_in[12]; P.stn2snr = (const float*)d_in[13];
  P.snr2thal= (const float*)d_in[14]; P.fsi2d1  = (const float*)d_in[15];
  P.fsi2d2  = (const float*)d_in[16]; P.thal2fsi= (const float*)d_in[17];
  P.alm2fsi = (const float*)d_in[18]; P.iti2fsi = (const float*)d_in[19];
  P.fsi2fsi = (const float*)d_in[20]; P.mask    = (const int*)d_in[21];
  const float* inp   = (const float*)d_in[22];
  const float* hn    = (const float*)d_in[23];
  const float* noise = (const float*)d_in[24];

  float* ws = (float*)d_ws;
  float* Wt = ws;
  float* h0 = ws + WT_FLOATS;
  float* h1 = h0 + TOT * BB;
  unsigned* bar = (unsigned*)(h1 + TOT * BB);

  hipLaunchKernelGGL(prep_wt,  dim3((WT_FLOATS + 255) / 256), dim3(256), 0, stream, P, Wt);
  hipLaunchKernelGGL(init_h,   dim3((TOT * BB + 255) / 256),  dim3(256), 0, stream, hn, h0);
  hipLaunchKernelGGL(zero_bar, dim3(1), dim3(512), 0, stream, bar);

  const float* WtA = Wt; const float* noiseA = noise; const float* inpA = inp;
  float* outA = (float*)d_out; float* h0A = h0; float* h1A = h1; unsigned* barA = bar;
  void* kargs[7] = {&WtA, &noiseA, &inpA, &outA, &h0A, &h1A, &barA};
  hipLaunchCooperativeKernel((const void*)rnn_scan, dim3(NWG), dim3(1024), kargs, 0, stream);
}

// Round 16
// 6031.317 us; speedup vs baseline: 3.9325x; 1.0626x over previous
//
#include <hip/hip_runtime.h>

#define TOT   3800
#define BB    8
#define TT    1000
#define AL    0.1f

constexpr int WT_FLOATS = 4475136;   // sum of padded region blocks
constexpr int NWG       = 241;       // ITI folded into FSI wg 9's padded rows
constexpr int CMAX      = 2304;      // padded packed-col count

// region order: D1, D2, FSI(+ITI), GPE, STN, SNR, THAL, ALM
__constant__ int   kWgStart[9]    = {0,33,66,76,109,142,175,208,241};
__constant__ int   kRowBase[8]    = {0,520,1040,1196,1716,2236,2756,3276};
__constant__ int   kRowCnt[8]     = {520,520,156,520,520,520,520,520};
__constant__ int   kCols[8]       = {2236,2236,1200,520,520,1040,520,1040};
__constant__ int   kWtOff[8]      = {0,1180608,2361216,2553216,2827776,3102336,3651456,3926016};
__constant__ int   kWtEnd[8]      = {1180608,2361216,2553216,2827776,3102336,3651456,3926016,4475136};
__constant__ float kTonic[8]      = {0.01f,0.01f,0.01f,0.8f,0.6f,0.8f,0.01f,0.01f};
// staging segments: packed col -> global h unit index
__constant__ int   kSegStart[8][3]= {{0,2756,0},{0,2756,0},{1040,2756,3796},{520,0,0},{1196,0,0},{0,1716,0},{2236,0,0},{2756,0,0}};
__constant__ int   kSegLen[8][3]  = {{1196,1040,0},{1196,1040,0},{156,1040,4},{520,0,0},{520,0,0},{520,520,0},{520,0,0},{1040,0,0}};

struct Params {
  const float *d12d1,*d22d2,*d12d2,*d22d1,*thal2alm,*thal2d1,*thal2d2,*alm2alm,
              *alm2d1,*alm2d2,*d12snr,*d22gpe,*gpe2stn,*stn2snr,*snr2thal,
              *fsi2d1,*fsi2d2,*thal2fsi,*alm2fsi,*iti2fsi,*fsi2fsi;
  const int* mask;
};

__device__ __forceinline__ float rl(float x) { return fmaxf(x, 0.0f); }

// Build packed, pre-masked, pre-signed, ALPHA-scaled W.
// Layout per region: offset = (ugg*cols + col)*4 + j, row = ugg*4 + j
__global__ void prep_wt(Params P, float* __restrict__ Wt) {
  int e = blockIdx.x * blockDim.x + threadIdx.x;
  if (e >= WT_FLOATS) return;
  int r = 0;
  while (e >= kWtEnd[r]) ++r;
  int base  = (r == 0) ? 0 : kWtEnd[r-1];
  int local = e - base;
  int j    = local & 3;
  int q    = local >> 2;
  int cols = kCols[r];
  int col  = q % cols;
  int ugg  = q / cols;
  int row  = ugg * 4 + j;
  float v = 0.0f;
  if (row < kRowCnt[r]) {
    int c = col;
    switch (r) {
      case 0: case 1: {
        const float* pd1 = (r==0) ? P.d12d1 : P.d12d2;
        const float* pd2 = (r==0) ? P.d22d1 : P.d22d2;
        const float* pf  = (r==0) ? P.fsi2d1 : P.fsi2d2;
        const float* pt  = (r==0) ? P.thal2d1 : P.thal2d2;
        const float* pa  = (r==0) ? P.alm2d1 : P.alm2d2;
        if (c < 520)       { v = -(float)P.mask[row*520+c] * rl(pd1[row*520+c]); }
        else if (c < 1040) { int cc=c-520;  v = -(float)P.mask[row*520+cc] * rl(pd2[row*520+cc]); }
        else if (c < 1196) { int cc=c-1040; v = -rl(pf[row*156+cc]); }
        else if (c < 1716) { int cc=c-1196; v =  rl(pt[row*520+cc]); }
        else               { int cc=c-1716; v = (cc<364) ? rl(pa[row*520+cc]) : 0.0f; }
        break;
      }
      case 2: {
        if (c < 156)       { v = -rl(P.fsi2fsi[row*156+c]); }
        else if (c < 676)  { int cc=c-156; v = rl(P.thal2fsi[row*520+cc]); }
        else if (c < 1196) { int cc=c-676; v = (cc<364) ? rl(P.alm2fsi[row*520+cc]) : 0.0f; }
        else               { int cc=c-1196; v = rl(P.iti2fsi[row*4+cc]); }
        break;
      }
      case 3: v = ((row<260)==(c<260)) ? -rl(P.d22gpe[row*520+c])  : 0.0f; break;
      case 4: v = ((row<260)==(c<260)) ? -rl(P.gpe2stn[row*520+c]) : 0.0f; break;
      case 5: {
        if (c < 520) { v = ((row<260)==(c<260)) ? -rl(P.d12snr[row*520+c]) : 0.0f; }
        else { int cc=c-520; v = ((row<260)==(cc<260)) ? rl(P.stn2snr[row*520+cc]) : 0.0f; }
        break;
      }
      case 6: v = ((row<260)==(c<260)) ? -rl(P.snr2thal[row*520+c]) : 0.0f; break;
      case 7: {
        if (c < 520) { v = rl(P.thal2alm[row*520+c]); }
        else { int cc=c-520; v = rl(P.alm2alm[row*520+cc]) * ((cc<364) ? 1.0f : -1.0f); }
        break;
      }
    }
    v *= AL;
  }
  Wt[e] = v;
}

// h is u-major: hT[u*8 + b] = hn[b*TOT + u]
__global__ void init_h(const float* __restrict__ hn, float* __restrict__ h0) {
  int i = blockIdx.x * blockDim.x + threadIdx.x;
  if (i < TOT * BB) {
    int u = i >> 3, b = i & 7;
    h0[i] = hn[b * TOT + u];
  }
}

__global__ void zero_bar(unsigned* __restrict__ bar) {
  if (threadIdx.x < 272) bar[threadIdx.x] = 0u;
}

__device__ __forceinline__ void agst(float* p, float v) {
  __hip_atomic_store(p, v, __ATOMIC_RELAXED, __HIP_MEMORY_SCOPE_AGENT);
}

#define CF(W, HX) \
  acc[0][b] = fmaf((W).x, (HX), acc[0][b]); \
  acc[1][b] = fmaf((W).y, (HX), acc[1][b]); \
  acc[2][b] = fmaf((W).z, (HX), acc[2][b]); \
  acc[3][b] = fmaf((W).w, (HX), acc[3][b]);

// R14 structure (proven no-spill: w[9]=36 VGPR, acc[4][8]=32, scalar epilogue,
// h in LDS [c][b] stride 12, b128 staging loads, cnt0-poll barrier,
// R4-exact partials/reduce). R16 delta (address-constant only):
// partials stride 260 -> 264. 264%32==8, so reduce-read banks are
// (8o+j)%32 over the 64 lanes = exactly 2 lanes/bank (free, m136);
// stride-260's (4o+j)%32 was up to 3-way — the 3.856e8 conflict counter
// constant across R11/R12/R14 localizes there.
__global__ void __launch_bounds__(1024, 4)
rnn_scan(const float* __restrict__ Wt, const float* __restrict__ noise,
         const float* __restrict__ inp, float* __restrict__ out,
         float* __restrict__ h0, float* __restrict__ h1,
         unsigned* __restrict__ bar) {
  __shared__ float S[33792];   // union: h [2304][12] (27648 f) / partials [128][264]
  const int bid = blockIdx.x, tid = threadIdx.x;
  int r = 0;
  while (bid >= kWgStart[r + 1]) ++r;

  unsigned* cnt1 = bar;          // 8 groups, stride 32 words (128B apart)
  unsigned* cnt0 = bar + 256;
  const int g8   = bid & 7;
  const unsigned gsz = (g8 == 0) ? 31u : 30u;

  const int wgl     = bid - kWgStart[r];
  const int cols    = kCols[r];
  const int rowcnt  = kRowCnt[r];
  const int rowbase = kRowBase[r];
  const int rg = tid >> 8, sp = tid & 255;
  const float* wtp = Wt + (size_t)kWtOff[r];
  const float ton = kTonic[r];
  const int l0 = kSegLen[r][0], l1 = kSegLen[r][1];
  const int g0 = kSegStart[r][0], g1 = kSegStart[r][1], g2 = kSegStart[r][2];

  // ---- W fragments: w[i] = quad-rows of col c = sp + 256*i  (36 VGPR)
  float4 w[9];
  {
    const int ug = wgl * 4 + rg;
    const float* wb = wtp + (size_t)ug * cols * 4;
    #pragma unroll
    for (int i = 0; i < 9; ++i) {
      int c = sp + (i << 8);
      w[i] = (c < cols) ? *(const float4*)(wb + (size_t)c * 4) : make_float4(0,0,0,0);
    }
  }

  // ---- staging tasks: task = c*2 + half (4608 tasks). Per task: 1 b128
  // agent load (unit g, batches half*4..+3) -> 4 adjacent LDS writes.
  // pk = ((go+1)<<13) | task ; go=-1 => zero-fill ; pk=-1 => no task
  int pkk[5];
  #pragma unroll
  for (int k2 = 0; k2 < 5; ++k2) {
    int task = tid + (k2 << 10);
    if (task < 2 * CMAX) {
      int c = task >> 1;
      int half = task & 1;
      int go = -1;
      if (c < cols) {
        int g;
        if (c < l0)           g = g0 + c;
        else if (c < l0 + l1) g = g1 + (c - l0);
        else                  g = g2 + (c - l0 - l1);
        go = g * 8 + half * 4;     // 16B-aligned element offset
      }
      pkk[k2] = ((go + 1) << 13) | task;
    } else pkk[k2] = -1;
  }

  // ---- epilogue role (R4-exact): threads with (tid&7)==0 own o = tid>>3 = (row,b)
  const int  j     = tid & 7;
  const int  o     = tid >> 3;          // 0..127  (= row16*8 + b)
  const int  erow  = o >> 3, eb = o & 7;
  const int  erowl = wgl * 16 + erow;
  const bool eiti  = (r == 2) && (wgl == 9) && (j == 0) && (erowl >= 156); // ITI fold
  const bool ewr   = (j == 0) && (erowl < rowcnt);
  const int  erg   = eiti ? (3796 + (erowl - 156)) : (rowbase + erowl);
  const bool own   = ewr || eiti;

  // prefetch step-0 epilogue operands; hp is carried thereafter (own row's output)
  float hp = 0.f, nz = 0.f, ii = 0.f;
  if (own) {
    hp = h0[erg * 8 + eb];
    nz = noise[((size_t)eb * TT) * TOT + erg];
    if (eiti) ii = inp[((size_t)eb * TT) * 4 + (erg - 3796)];
  }

  for (int t = 0; t < TT; ++t) {
    const float* __restrict__ hc = (t & 1) ? h1 : h0;
    float*       __restrict__ hx = (t & 1) ? h0 : h1;

    // ---- stage h: issue all b128 agent loads, single vmcnt, write to LDS
    float4 vv[5];
    #pragma unroll
    for (int k2 = 0; k2 < 5; ++k2) {
      int pk = pkk[k2];
      if (pk >= 0) {
        int go = (pk >> 13) - 1;
        if (go >= 0) {
          const float* p = hc + go;
          asm volatile("global_load_dwordx4 %0, %1, off sc0 sc1"
                       : "=v"(vv[k2]) : "v"(p));
        } else {
          vv[k2] = make_float4(0.f, 0.f, 0.f, 0.f);
        }
      }
    }
    asm volatile("s_waitcnt vmcnt(0)" ::: "memory");
    #pragma unroll
    for (int k2 = 0; k2 < 5; ++k2) {
      int pk = pkk[k2];
      if (pk >= 0) {
        int task = pk & 8191;
        int c    = task >> 1;
        int half = task & 1;
        int ds   = c * 12 + half * 4;   // 16B-aligned -> b128-fusable
        S[ds + 0] = vv[k2].x;
        S[ds + 1] = vv[k2].y;
        S[ds + 2] = vv[k2].z;
        S[ds + 3] = vv[k2].w;
      }
    }
    __syncthreads();

    // ---- FMA burst: 8 adjacent reads per col (b128/read2-fusable), 288 fmaf
    float acc[4][8];
    #pragma unroll
    for (int r2 = 0; r2 < 4; ++r2)
      #pragma unroll
      for (int b = 0; b < 8; ++b) acc[r2][b] = 0.f;

    #pragma unroll
    for (int i = 0; i < 9; ++i) {
      const float4 wv = w[i];
      const int cb = (sp + (i << 8)) * 12;
      #pragma unroll
      for (int b = 0; b < 8; ++b) {
        const float h = S[cb + b];
        CF(wv, h)
      }
    }
    __syncthreads();   // done reading h; reuse S as partials

    // ---- partials (R4 layout, stride 264): S[((rg*4+r2)*8+b)*264 + sp]
    #pragma unroll
    for (int r2 = 0; r2 < 4; ++r2)
      #pragma unroll
      for (int b = 0; b < 8; ++b)
        S[((rg * 4 + r2) * 8 + b) * 264 + sp] = acc[r2][b];
    __syncthreads();

    // ---- reduce (R4 pattern, stride 264): thread (o,j) sums sp = j+8k, 3x shfl
    float s = 0.f;
    #pragma unroll
    for (int k = 0; k < 32; ++k) s += S[o * 264 + j + (k << 3)];
    s += __shfl_xor(s, 1);
    s += __shfl_xor(s, 2);
    s += __shfl_xor(s, 4);

    float x = 0.f;
    if (eiti)     x = fmaxf(fmaf(0.9f, hp, AL * (nz + ii)), 0.0f);
    else if (ewr) x = fmaxf(fmaf(0.9f, hp, s + AL * (ton + nz)), 0.0f);
    if (own) agst(&hx[erg * 8 + eb], x);   // LLC-coherent store
    __syncthreads();   // drain hx stores (vmcnt(0) before s_barrier)

    // ---- arrive: 2-level, release through LLC (stores acked at sync above)
    if (tid == 0) {
      unsigned old = atomicAdd(&cnt1[g8 * 32], 1u);
      if (old + 1 == gsz * (unsigned)(t + 1)) {
        atomicAdd(cnt0, 1u);     // 8th add for step t makes cnt0 == 8*(t+1)
      }
    }

    // ---- independent work hidden under the barrier: out-store + t+1 prefetch
    if (own) {
      out[((size_t)eb * TT + t) * TOT + erg] = x;
      hp = x;                               // own row's h_prev for t+1
      if (t + 1 < TT) {
        nz = noise[((size_t)eb * TT + (t + 1)) * TOT + erg];
        if (eiti) ii = inp[((size_t)eb * TT + (t + 1)) * 4 + (erg - 3796)];
      }
    }

    // ---- wait: poll cnt0 directly
    if (tid == 0) {
      while (__hip_atomic_load(cnt0, __ATOMIC_RELAXED, __HIP_MEMORY_SCOPE_AGENT)
             < 8u * (unsigned)(t + 1)) {}
    }
    __syncthreads();
  }
}

extern "C" void kernel_launch(void* const* d_in, const int* in_sizes, int n_in,
                              void* d_out, int out_size, void* d_ws, size_t ws_size,
                              hipStream_t stream) {
  Params P;
  P.d12d1   = (const float*)d_in[0];  P.d22d2   = (const float*)d_in[1];
  P.d12d2   = (const float*)d_in[2];  P.d22d1   = (const float*)d_in[3];
  P.thal2alm= (const float*)d_in[4];  P.thal2d1 = (const float*)d_in[5];
  P.thal2d2 = (const float*)d_in[6];  P.alm2alm = (const float*)d_in[7];
  P.alm2d1  = (const float*)d_in[8];  P.alm2d2  = (const float*)d_in[9];
  P.d12snr  = (const float*)d_in[10]; P.d22gpe  = (const float*)d_in[11];
  P.gpe2stn = (const float*)d_in[12]; P.stn2snr = (const float*)d_in[13];
  P.snr2thal= (const float*)d_in[14]; P.fsi2d1  = (const float*)d_in[15];
  P.fsi2d2  = (const float*)d_in[16]; P.thal2fsi= (const float*)d_in[17];
  P.alm2fsi = (const float*)d_in[18]; P.iti2fsi = (const float*)d_in[19];
  P.fsi2fsi = (const float*)d_in[20]; P.mask    = (const int*)d_in[21];
  const float* inp   = (const float*)d_in[22];
  const float* hn    = (const float*)d_in[23];
  const float* noise = (const float*)d_in[24];

  float* ws = (float*)d_ws;
  float* Wt = ws;
  float* h0 = ws + WT_FLOATS;
  float* h1 = h0 + TOT * BB;
  unsigned* bar = (unsigned*)(h1 + TOT * BB);

  hipLaunchKernelGGL(prep_wt,  dim3((WT_FLOATS + 255) / 256), dim3(256), 0, stream, P, Wt);
  hipLaunchKernelGGL(init_h,   dim3((TOT * BB + 255) / 256),  dim3(256), 0, stream, hn, h0);
  hipLaunchKernelGGL(zero_bar, dim3(1), dim3(512), 0, stream, bar);

  const float* WtA = Wt; const float* noiseA = noise; const float* inpA = inp;
  float* outA = (float*)d_out; float* h0A = h0; float* h1A = h1; unsigned* barA = bar;
  void* kargs[7] = {&WtA, &noiseA, &inpA, &outA, &h0A, &h1A, &barA};
  hipLaunchCooperativeKernel((const void*)rnn_scan, dim3(NWG), dim3(1024), kargs, 0, stream);
}

// Round 18
// 6008.640 us; speedup vs baseline: 3.9473x; 1.0038x over previous
//
#include <hip/hip_runtime.h>

#define TOT   3800
#define BB    8
#define TT    1000
#define AL    0.1f

constexpr int WT_FLOATS = 4475136;   // sum of padded region blocks
constexpr int NWG       = 241;       // ITI folded into FSI wg 9's padded rows
constexpr int CMAX      = 2304;      // padded packed-col count

// region order: D1, D2, FSI(+ITI), GPE, STN, SNR, THAL, ALM
__constant__ int   kWgStart[9]    = {0,33,66,76,109,142,175,208,241};
__constant__ int   kRowBase[8]    = {0,520,1040,1196,1716,2236,2756,3276};
__constant__ int   kRowCnt[8]     = {520,520,156,520,520,520,520,520};
__constant__ int   kCols[8]       = {2236,2236,1200,520,520,1040,520,1040};
__constant__ int   kWtOff[8]      = {0,1180608,2361216,2553216,2827776,3102336,3651456,3926016};
__constant__ int   kWtEnd[8]      = {1180608,2361216,2553216,2827776,3102336,3651456,3926016,4475136};
__constant__ float kTonic[8]      = {0.01f,0.01f,0.01f,0.8f,0.6f,0.8f,0.01f,0.01f};
// staging segments: packed col -> global h unit index
__constant__ int   kSegStart[8][3]= {{0,2756,0},{0,2756,0},{1040,2756,3796},{520,0,0},{1196,0,0},{0,1716,0},{2236,0,0},{2756,0,0}};
__constant__ int   kSegLen[8][3]  = {{1196,1040,0},{1196,1040,0},{156,1040,4},{520,0,0},{520,0,0},{520,520,0},{520,0,0},{1040,0,0}};

struct Params {
  const float *d12d1,*d22d2,*d12d2,*d22d1,*thal2alm,*thal2d1,*thal2d2,*alm2alm,
              *alm2d1,*alm2d2,*d12snr,*d22gpe,*gpe2stn,*stn2snr,*snr2thal,
              *fsi2d1,*fsi2d2,*thal2fsi,*alm2fsi,*iti2fsi,*fsi2fsi;
  const int* mask;
};

__device__ __forceinline__ float rl(float x) { return fmaxf(x, 0.0f); }

// Build packed, pre-masked, pre-signed, ALPHA-scaled W.
// Layout per region: offset = (ugg*cols + col)*4 + j, row = ugg*4 + j
__global__ void prep_wt(Params P, float* __restrict__ Wt) {
  int e = blockIdx.x * blockDim.x + threadIdx.x;
  if (e >= WT_FLOATS) return;
  int r = 0;
  while (e >= kWtEnd[r]) ++r;
  int base  = (r == 0) ? 0 : kWtEnd[r-1];
  int local = e - base;
  int j    = local & 3;
  int q    = local >> 2;
  int cols = kCols[r];
  int col  = q % cols;
  int ugg  = q / cols;
  int row  = ugg * 4 + j;
  float v = 0.0f;
  if (row < kRowCnt[r]) {
    int c = col;
    switch (r) {
      case 0: case 1: {
        const float* pd1 = (r==0) ? P.d12d1 : P.d12d2;
        const float* pd2 = (r==0) ? P.d22d1 : P.d22d2;
        const float* pf  = (r==0) ? P.fsi2d1 : P.fsi2d2;
        const float* pt  = (r==0) ? P.thal2d1 : P.thal2d2;
        const float* pa  = (r==0) ? P.alm2d1 : P.alm2d2;
        if (c < 520)       { v = -(float)P.mask[row*520+c] * rl(pd1[row*520+c]); }
        else if (c < 1040) { int cc=c-520;  v = -(float)P.mask[row*520+cc] * rl(pd2[row*520+cc]); }
        else if (c < 1196) { int cc=c-1040; v = -rl(pf[row*156+cc]); }
        else if (c < 1716) { int cc=c-1196; v =  rl(pt[row*520+cc]); }
        else               { int cc=c-1716; v = (cc<364) ? rl(pa[row*520+cc]) : 0.0f; }
        break;
      }
      case 2: {
        if (c < 156)       { v = -rl(P.fsi2fsi[row*156+c]); }
        else if (c < 676)  { int cc=c-156; v = rl(P.thal2fsi[row*520+cc]); }
        else if (c < 1196) { int cc=c-676; v = (cc<364) ? rl(P.alm2fsi[row*520+cc]) : 0.0f; }
        else               { int cc=c-1196; v = rl(P.iti2fsi[row*4+cc]); }
        break;
      }
      case 3: v = ((row<260)==(c<260)) ? -rl(P.d22gpe[row*520+c])  : 0.0f; break;
      case 4: v = ((row<260)==(c<260)) ? -rl(P.gpe2stn[row*520+c]) : 0.0f; break;
      case 5: {
        if (c < 520) { v = ((row<260)==(c<260)) ? -rl(P.d12snr[row*520+c]) : 0.0f; }
        else { int cc=c-520; v = ((row<260)==(cc<260)) ? rl(P.stn2snr[row*520+cc]) : 0.0f; }
        break;
      }
      case 6: v = ((row<260)==(c<260)) ? -rl(P.snr2thal[row*520+c]) : 0.0f; break;
      case 7: {
        if (c < 520) { v = rl(P.thal2alm[row*520+c]); }
        else { int cc=c-520; v = rl(P.alm2alm[row*520+cc]) * ((cc<364) ? 1.0f : -1.0f); }
        break;
      }
    }
    v *= AL;
  }
  Wt[e] = v;
}

// h is u-major: hT[u*8 + b] = hn[b*TOT + u]
__global__ void init_h(const float* __restrict__ hn, float* __restrict__ h0) {
  int i = blockIdx.x * blockDim.x + threadIdx.x;
  if (i < TOT * BB) {
    int u = i >> 3, b = i & 7;
    h0[i] = hn[b * TOT + u];
  }
}

__global__ void zero_bar(unsigned* __restrict__ bar) {
  if (threadIdx.x < 272) bar[threadIdx.x] = 0u;
}

__device__ __forceinline__ void agst(float* p, float v) {
  __hip_atomic_store(p, v, __ATOMIC_RELAXED, __HIP_MEMORY_SCOPE_AGENT);
}

#define CF(W, HX) \
  acc[0][b] = fmaf((W).x, (HX), acc[0][b]); \
  acc[1][b] = fmaf((W).y, (HX), acc[1][b]); \
  acc[2][b] = fmaf((W).z, (HX), acc[2][b]); \
  acc[3][b] = fmaf((W).w, (HX), acc[3][b]);

// R16 final (best passing, 6031 us): w[9]=36 VGPR + acc[4][8]=32, scalar
// epilogue (the only no-spill shape at the 1024-thread 64-VGPR wall);
// h in LDS [c][b] stride 12 (16B-aligned -> b128 staging writes + fused
// inner reads, banks tile all 32); partials stride 264 (>=256 for sp range,
// 264%32==8 -> 2-lanes/bank reduce, conflicts 3.9e8 -> 1.4e8); single-b128
// sc0/sc1 staging loads with one vmcnt; 2-level cnt1/cnt0 LLC barrier with
// direct cnt0 poll; out-store + noise prefetch hidden under the barrier.
// Partials/reduce phase is at its floor: fusion requires pair offsets <=255
// dwords, correctness requires row stride >=256 (R17's failure) — exclusive.
__global__ void __launch_bounds__(1024, 4)
rnn_scan(const float* __restrict__ Wt, const float* __restrict__ noise,
         const float* __restrict__ inp, float* __restrict__ out,
         float* __restrict__ h0, float* __restrict__ h1,
         unsigned* __restrict__ bar) {
  __shared__ float S[33792];   // union: h [2304][12] (27648 f) / partials [128][264]
  const int bid = blockIdx.x, tid = threadIdx.x;
  int r = 0;
  while (bid >= kWgStart[r + 1]) ++r;

  unsigned* cnt1 = bar;          // 8 groups, stride 32 words (128B apart)
  unsigned* cnt0 = bar + 256;
  const int g8   = bid & 7;
  const unsigned gsz = (g8 == 0) ? 31u : 30u;

  const int wgl     = bid - kWgStart[r];
  const int cols    = kCols[r];
  const int rowcnt  = kRowCnt[r];
  const int rowbase = kRowBase[r];
  const int rg = tid >> 8, sp = tid & 255;
  const float* wtp = Wt + (size_t)kWtOff[r];
  const float ton = kTonic[r];
  const int l0 = kSegLen[r][0], l1 = kSegLen[r][1];
  const int g0 = kSegStart[r][0], g1 = kSegStart[r][1], g2 = kSegStart[r][2];

  // ---- W fragments: w[i] = quad-rows of col c = sp + 256*i  (36 VGPR)
  float4 w[9];
  {
    const int ug = wgl * 4 + rg;
    const float* wb = wtp + (size_t)ug * cols * 4;
    #pragma unroll
    for (int i = 0; i < 9; ++i) {
      int c = sp + (i << 8);
      w[i] = (c < cols) ? *(const float4*)(wb + (size_t)c * 4) : make_float4(0,0,0,0);
    }
  }

  // ---- staging tasks: task = c*2 + half (4608 tasks). Per task: 1 b128
  // agent load (unit g, batches half*4..+3) -> 4 adjacent LDS writes.
  // pk = ((go+1)<<13) | task ; go=-1 => zero-fill ; pk=-1 => no task
  int pkk[5];
  #pragma unroll
  for (int k2 = 0; k2 < 5; ++k2) {
    int task = tid + (k2 << 10);
    if (task < 2 * CMAX) {
      int c = task >> 1;
      int half = task & 1;
      int go = -1;
      if (c < cols) {
        int g;
        if (c < l0)           g = g0 + c;
        else if (c < l0 + l1) g = g1 + (c - l0);
        else                  g = g2 + (c - l0 - l1);
        go = g * 8 + half * 4;     // 16B-aligned element offset
      }
      pkk[k2] = ((go + 1) << 13) | task;
    } else pkk[k2] = -1;
  }

  // ---- epilogue role (R4-exact): threads with (tid&7)==0 own o = tid>>3 = (row,b)
  const int  j     = tid & 7;
  const int  o     = tid >> 3;          // 0..127  (= row16*8 + b)
  const int  erow  = o >> 3, eb = o & 7;
  const int  erowl = wgl * 16 + erow;
  const bool eiti  = (r == 2) && (wgl == 9) && (j == 0) && (erowl >= 156); // ITI fold
  const bool ewr   = (j == 0) && (erowl < rowcnt);
  const int  erg   = eiti ? (3796 + (erowl - 156)) : (rowbase + erowl);
  const bool own   = ewr || eiti;

  // prefetch step-0 epilogue operands; hp is carried thereafter (own row's output)
  float hp = 0.f, nz = 0.f, ii = 0.f;
  if (own) {
    hp = h0[erg * 8 + eb];
    nz = noise[((size_t)eb * TT) * TOT + erg];
    if (eiti) ii = inp[((size_t)eb * TT) * 4 + (erg - 3796)];
  }

  for (int t = 0; t < TT; ++t) {
    const float* __restrict__ hc = (t & 1) ? h1 : h0;
    float*       __restrict__ hx = (t & 1) ? h0 : h1;

    // ---- stage h: issue all b128 agent loads, single vmcnt, write to LDS
    float4 vv[5];
    #pragma unroll
    for (int k2 = 0; k2 < 5; ++k2) {
      int pk = pkk[k2];
      if (pk >= 0) {
        int go = (pk >> 13) - 1;
        if (go >= 0) {
          const float* p = hc + go;
          asm volatile("global_load_dwordx4 %0, %1, off sc0 sc1"
                       : "=v"(vv[k2]) : "v"(p));
        } else {
          vv[k2] = make_float4(0.f, 0.f, 0.f, 0.f);
        }
      }
    }
    asm volatile("s_waitcnt vmcnt(0)" ::: "memory");
    #pragma unroll
    for (int k2 = 0; k2 < 5; ++k2) {
      int pk = pkk[k2];
      if (pk >= 0) {
        int task = pk & 8191;
        int c    = task >> 1;
        int half = task & 1;
        int ds   = c * 12 + half * 4;   // 16B-aligned -> b128-fusable
        S[ds + 0] = vv[k2].x;
        S[ds + 1] = vv[k2].y;
        S[ds + 2] = vv[k2].z;
        S[ds + 3] = vv[k2].w;
      }
    }
    __syncthreads();

    // ---- FMA burst: 8 adjacent reads per col (b128/read2-fusable), 288 fmaf
    float acc[4][8];
    #pragma unroll
    for (int r2 = 0; r2 < 4; ++r2)
      #pragma unroll
      for (int b = 0; b < 8; ++b) acc[r2][b] = 0.f;

    #pragma unroll
    for (int i = 0; i < 9; ++i) {
      const float4 wv = w[i];
      const int cb = (sp + (i << 8)) * 12;
      #pragma unroll
      for (int b = 0; b < 8; ++b) {
        const float h = S[cb + b];
        CF(wv, h)
      }
    }
    __syncthreads();   // done reading h; reuse S as partials

    // ---- partials (stride 264): S[((rg*4+r2)*8+b)*264 + sp]
    #pragma unroll
    for (int r2 = 0; r2 < 4; ++r2)
      #pragma unroll
      for (int b = 0; b < 8; ++b)
        S[((rg * 4 + r2) * 8 + b) * 264 + sp] = acc[r2][b];
    __syncthreads();

    // ---- reduce (stride 264): thread (o,j) sums sp = j+8k, then 3x shfl_xor
    float s = 0.f;
    #pragma unroll
    for (int k = 0; k < 32; ++k) s += S[o * 264 + j + (k << 3)];
    s += __shfl_xor(s, 1);
    s += __shfl_xor(s, 2);
    s += __shfl_xor(s, 4);

    float x = 0.f;
    if (eiti)     x = fmaxf(fmaf(0.9f, hp, AL * (nz + ii)), 0.0f);
    else if (ewr) x = fmaxf(fmaf(0.9f, hp, s + AL * (ton + nz)), 0.0f);
    if (own) agst(&hx[erg * 8 + eb], x);   // LLC-coherent store
    __syncthreads();   // drain hx stores (vmcnt(0) before s_barrier)

    // ---- arrive: 2-level, release through LLC (stores acked at sync above)
    if (tid == 0) {
      unsigned old = atomicAdd(&cnt1[g8 * 32], 1u);
      if (old + 1 == gsz * (unsigned)(t + 1)) {
        atomicAdd(cnt0, 1u);     // 8th add for step t makes cnt0 == 8*(t+1)
      }
    }

    // ---- independent work hidden under the barrier: out-store + t+1 prefetch
    if (own) {
      out[((size_t)eb * TT + t) * TOT + erg] = x;
      hp = x;                               // own row's h_prev for t+1
      if (t + 1 < TT) {
        nz = noise[((size_t)eb * TT + (t + 1)) * TOT + erg];
        if (eiti) ii = inp[((size_t)eb * TT + (t + 1)) * 4 + (erg - 3796)];
      }
    }

    // ---- wait: poll cnt0 directly
    if (tid == 0) {
      while (__hip_atomic_load(cnt0, __ATOMIC_RELAXED, __HIP_MEMORY_SCOPE_AGENT)
             < 8u * (unsigned)(t + 1)) {}
    }
    __syncthreads();
  }
}

extern "C" void kernel_launch(void* const* d_in, const int* in_sizes, int n_in,
                              void* d_out, int out_size, void* d_ws, size_t ws_size,
                              hipStream_t stream) {
  Params P;
  P.d12d1   = (const float*)d_in[0];  P.d22d2   = (const float*)d_in[1];
  P.d12d2   = (const float*)d_in[2];  P.d22d1   = (const float*)d_in[3];
  P.thal2alm= (const float*)d_in[4];  P.thal2d1 = (const float*)d_in[5];
  P.thal2d2 = (const float*)d_in[6];  P.alm2alm = (const float*)d_in[7];
  P.alm2d1  = (const float*)d_in[8];  P.alm2d2  = (const float*)d_in[9];
  P.d12snr  = (const float*)d_in[10]; P.d22gpe  = (const float*)d_in[11];
  P.gpe2stn = (const float*)d_in[12]; P.stn2snr = (const float*)d_in[13];
  P.snr2thal= (const float*)d_in[14]; P.fsi2d1  = (const float*)d_in[15];
  P.fsi2d2  = (const float*)d_in[16]; P.thal2fsi= (const float*)d_in[17];
  P.alm2fsi = (const float*)d_in[18]; P.iti2fsi = (const float*)d_in[19];
  P.fsi2fsi = (const float*)d_in[20]; P.mask    = (const int*)d_in[21];
  const float* inp   = (const float*)d_in[22];
  const float* hn    = (const float*)d_in[23];
  const float* noise = (const float*)d_in[24];

  float* ws = (float*)d_ws;
  float* Wt = ws;
  float* h0 = ws + WT_FLOATS;
  float* h1 = h0 + TOT * BB;
  unsigned* bar = (unsigned*)(h1 + TOT * BB);

  hipLaunchKernelGGL(prep_wt,  dim3((WT_FLOATS + 255) / 256), dim3(256), 0, stream, P, Wt);
  hipLaunchKernelGGL(init_h,   dim3((TOT * BB + 255) / 256),  dim3(256), 0, stream, hn, h0);
  hipLaunchKernelGGL(zero_bar, dim3(1), dim3(512), 0, stream, bar);

  const float* WtA = Wt; const float* noiseA = noise; const float* inpA = inp;
  float* outA = (float*)d_out; float* h0A = h0; float* h1A = h1; unsigned* barA = bar;
  void* kargs[7] = {&WtA, &noiseA, &inpA, &outA, &h0A, &h1A, &barA};
  hipLaunchCooperativeKernel((const void*)rnn_scan, dim3(NWG), dim3(1024), kargs, 0, stream);
}